// Round 1
// baseline (795.499 us; speedup 1.0000x reference)
//
#include <hip/hip_runtime.h>
#include <hip/hip_bf16.h>

#define DM   1024
#define DFF  4096
#define NB   4
#define SS   2048
#define NH   16
#define DK   64
#define MROWS (NB*SS)   // 8192

typedef __attribute__((ext_vector_type(8))) short bfx8;
typedef __attribute__((ext_vector_type(4))) float fx4;

static __device__ __forceinline__ unsigned short f2bf(float f) {
  union { __hip_bfloat16 h; unsigned short u; } cv;
  cv.h = __float2bfloat16(f);
  return cv.u;
}

static __device__ __forceinline__ void async16(void* lds, const void* g) {
  typedef const __attribute__((address_space(1))) unsigned int* gp_t;
  typedef __attribute__((address_space(3))) unsigned int* lp_t;
  __builtin_amdgcn_global_load_lds((gp_t)g, (lp_t)lds, 16, 0, 0);
}

// ---------------- weight transpose + f32->bf16 cast: out[n][k] = in[k][n] ----
__global__ __launch_bounds__(256) void k_transpose(const float* __restrict__ in,
                                                   unsigned short* __restrict__ out,
                                                   int K, int N) {
  __shared__ float t[32][33];
  const int n0 = blockIdx.x * 32, k0 = blockIdx.y * 32;
  const int tx = threadIdx.x & 31, ty = threadIdx.x >> 5;  // 32 x 8
#pragma unroll
  for (int j = 0; j < 4; j++)
    t[ty + j * 8][tx] = in[(size_t)(k0 + ty + j * 8) * N + n0 + tx];
  __syncthreads();
#pragma unroll
  for (int j = 0; j < 4; j++)
    out[(size_t)(n0 + ty + j * 8) * K + k0 + tx] = f2bf(t[tx][ty + j * 8]);
}

// ---------------- layernorm: f32 in -> bf16 out, one wave per row ----------
__global__ __launch_bounds__(256) void k_layernorm(const float* __restrict__ x,
                                                   const float* __restrict__ g,
                                                   const float* __restrict__ b,
                                                   unsigned short* __restrict__ out) {
  const int row  = blockIdx.x * 4 + (threadIdx.x >> 6);
  const int lane = threadIdx.x & 63;
  const float* xr = x + (size_t)row * DM;
  float4 vb[4];
  float s = 0.f, s2 = 0.f;
#pragma unroll
  for (int j = 0; j < 4; j++) {
    float4 v = *(const float4*)(xr + j * 256 + lane * 4);
    vb[j] = v;
    s  += v.x + v.y + v.z + v.w;
    s2 += v.x * v.x + v.y * v.y + v.z * v.z + v.w * v.w;
  }
#pragma unroll
  for (int off = 1; off < 64; off <<= 1) {
    s  += __shfl_xor(s,  off);
    s2 += __shfl_xor(s2, off);
  }
  const float mu   = s * (1.f / DM);
  const float var  = s2 * (1.f / DM) - mu * mu;
  const float rstd = rsqrtf(var + 1e-5f);
  unsigned short* orow = out + (size_t)row * DM;
#pragma unroll
  for (int j = 0; j < 4; j++) {
    const int col = j * 256 + lane * 4;
    float vv[4] = {vb[j].x, vb[j].y, vb[j].z, vb[j].w};
    unsigned int lo, hi;
    unsigned short e0 = f2bf((vv[0] - mu) * rstd * g[col + 0] + b[col + 0]);
    unsigned short e1 = f2bf((vv[1] - mu) * rstd * g[col + 1] + b[col + 1]);
    unsigned short e2 = f2bf((vv[2] - mu) * rstd * g[col + 2] + b[col + 2]);
    unsigned short e3 = f2bf((vv[3] - mu) * rstd * g[col + 3] + b[col + 3]);
    lo = (unsigned int)e0 | ((unsigned int)e1 << 16);
    hi = (unsigned int)e2 | ((unsigned int)e3 << 16);
    uint2 o; o.x = lo; o.y = hi;
    *(uint2*)(orow + col) = o;
  }
}

// ---------------- GEMM: C[M,N] = A[M,K](bf16) @ BT[N,K](bf16)^T + bias -----
// EPI: 0 = bf16 out, 1 = f32 out (+res), 2 = bf16 gelu out
template <int EPI>
__global__ __launch_bounds__(256) void k_gemm_bt(const unsigned short* __restrict__ A,
                                                 const unsigned short* __restrict__ BT,
                                                 const float* __restrict__ bias,
                                                 const float* __restrict__ res,
                                                 void* __restrict__ outp,
                                                 int M, int N, int K) {
  __shared__ unsigned short Al[128 * 32];
  __shared__ unsigned short Bl[128 * 32];
  const int tid = threadIdx.x, wave = tid >> 6, lane = tid & 63;
  const int m0 = blockIdx.y * 128, n0 = blockIdx.x * 128;
  const int wm = (wave >> 1) * 64, wn = (wave & 1) * 64;
  const int la = lane & 15, lg = lane >> 4;
  fx4 acc[4][4];
#pragma unroll
  for (int i = 0; i < 4; i++)
#pragma unroll
    for (int j = 0; j < 4; j++) acc[i][j] = fx4{0.f, 0.f, 0.f, 0.f};

  const unsigned short* ga = A  + (size_t)(m0 + wave * 32 + (lane >> 2)) * K + (lane & 3) * 8;
  const unsigned short* gb = BT + (size_t)(n0 + wave * 32 + (lane >> 2)) * K + (lane & 3) * 8;
  char* lA = (char*)Al + wave * 2048;
  char* lB = (char*)Bl + wave * 2048;

  for (int k0 = 0; k0 < K; k0 += 32) {
    async16(lA,        ga + k0);
    async16(lA + 1024, ga + 16 * (size_t)K + k0);
    async16(lB,        gb + k0);
    async16(lB + 1024, gb + 16 * (size_t)K + k0);
    __syncthreads();
    bfx8 av[4], bv[4];
#pragma unroll
    for (int mt = 0; mt < 4; mt++)
      av[mt] = *(const bfx8*)((const char*)Al + (wm + mt * 16 + la) * 64 + lg * 16);
#pragma unroll
    for (int nt = 0; nt < 4; nt++)
      bv[nt] = *(const bfx8*)((const char*)Bl + (wn + nt * 16 + la) * 64 + lg * 16);
#pragma unroll
    for (int mt = 0; mt < 4; mt++)
#pragma unroll
      for (int nt = 0; nt < 4; nt++)
        acc[mt][nt] = __builtin_amdgcn_mfma_f32_16x16x32_bf16(av[mt], bv[nt], acc[mt][nt], 0, 0, 0);
    __syncthreads();
  }

#pragma unroll
  for (int nt = 0; nt < 4; nt++) {
    const int n = n0 + wn + nt * 16 + la;
    const float bs = bias[n];
#pragma unroll
    for (int mt = 0; mt < 4; mt++) {
#pragma unroll
      for (int vv = 0; vv < 4; vv++) {
        const int m = m0 + wm + mt * 16 + lg * 4 + vv;
        const float val = acc[mt][nt][vv] + bs;
        const size_t idx = (size_t)m * N + n;
        if constexpr (EPI == 1) {
          ((float*)outp)[idx] = res[idx] + val;
        } else if constexpr (EPI == 2) {
          const float gl = 0.5f * val * (1.f + erff(val * 0.70710678118f));
          ((unsigned short*)outp)[idx] = f2bf(gl);
        } else {
          ((unsigned short*)outp)[idx] = f2bf(val);
        }
      }
    }
  }
}

// ---------------- causal flash attention, bf16 MFMA ------------------------
// grid: (S/64, NH, NB); block 256 (4 waves x 16 q-rows). KV chunks of 32.
__global__ __launch_bounds__(256) void k_attn(const unsigned short* __restrict__ q,
                                              const unsigned short* __restrict__ k,
                                              const unsigned short* __restrict__ v,
                                              unsigned short* __restrict__ att) {
  __shared__ unsigned short Kl[32][72];      // padded: 144B rows (16B aligned)
  __shared__ unsigned short Vt[64][40];      // V^T, padded: 80B rows
  __shared__ unsigned short Pl[4][16][40];   // per-wave P re-layout buffer
  const int bq = blockIdx.x, h = blockIdx.y, b = blockIdx.z;
  const int tid = threadIdx.x, wave = tid >> 6, lane = tid & 63;
  const int la = lane & 15, lg = lane >> 4;
  const int q0 = bq * 64;
  const int qrow = q0 + wave * 16;

  const unsigned short* qbase = q + ((size_t)(b * SS + qrow + la)) * DM + h * DK;
  bfx8 qf0 = *(const bfx8*)(qbase + lg * 8);
  bfx8 qf1 = *(const bfx8*)(qbase + 32 + lg * 8);

  fx4 acc[4];
#pragma unroll
  for (int nt = 0; nt < 4; nt++) acc[nt] = fx4{0.f, 0.f, 0.f, 0.f};
  float mrun[4], lrun[4];
#pragma unroll
  for (int i = 0; i < 4; i++) { mrun[i] = -1e30f; lrun[i] = 0.f; }

  const int nchunks = (q0 + 64) / 32;
  const int sr = tid >> 3, sc = (tid & 7) * 8;  // staging: row 0..31, col step 8
  const unsigned short* kg = k + ((size_t)(b * SS + sr)) * DM + h * DK + sc;
  const unsigned short* vg = v + ((size_t)(b * SS + sr)) * DM + h * DK + sc;

  for (int ch = 0; ch < nchunks; ch++) {
    const int c0 = ch * 32;
    // ---- stage K (row-major) and V (transposed) ----
    uint4 kk4 = *(const uint4*)(kg + (size_t)c0 * DM);
    uint4 vv4 = *(const uint4*)(vg + (size_t)c0 * DM);
    *(uint4*)&Kl[sr][sc] = kk4;
    const unsigned short* vs = (const unsigned short*)&vv4;
#pragma unroll
    for (int j = 0; j < 8; j++) Vt[sc + j][sr] = vs[j];
    __syncthreads();

    // ---- S = Q K^T (two 16x16 tiles over this 32-chunk) ----
    fx4 st[2];
#pragma unroll
    for (int t = 0; t < 2; t++) {
      bfx8 kf0 = *(const bfx8*)&Kl[t * 16 + la][lg * 8];
      bfx8 kf1 = *(const bfx8*)&Kl[t * 16 + la][32 + lg * 8];
      fx4 z = fx4{0.f, 0.f, 0.f, 0.f};
      z = __builtin_amdgcn_mfma_f32_16x16x32_bf16(qf0, kf0, z, 0, 0, 0);
      z = __builtin_amdgcn_mfma_f32_16x16x32_bf16(qf1, kf1, z, 0, 0, 0);
      st[t] = z;
    }
    // ---- scale + causal mask ----
#pragma unroll
    for (int t = 0; t < 2; t++)
#pragma unroll
      for (int vi = 0; vi < 4; vi++) {
        const int qr = qrow + lg * 4 + vi;
        const int kc = c0 + t * 16 + la;
        const float sv = st[t][vi] * 0.125f;
        st[t][vi] = (kc > qr) ? -1e30f : sv;
      }
    // ---- online softmax ----
#pragma unroll
    for (int vi = 0; vi < 4; vi++) {
      float mx = fmaxf(st[0][vi], st[1][vi]);
      mx = fmaxf(mx, __shfl_xor(mx, 1));
      mx = fmaxf(mx, __shfl_xor(mx, 2));
      mx = fmaxf(mx, __shfl_xor(mx, 4));
      mx = fmaxf(mx, __shfl_xor(mx, 8));
      const float mn = fmaxf(mrun[vi], mx);
      const float scale = __expf(mrun[vi] - mn);
      const float p0 = __expf(st[0][vi] - mn);
      const float p1 = __expf(st[1][vi] - mn);
      float ps = p0 + p1;
      ps += __shfl_xor(ps, 1);
      ps += __shfl_xor(ps, 2);
      ps += __shfl_xor(ps, 4);
      ps += __shfl_xor(ps, 8);
      lrun[vi] = lrun[vi] * scale + ps;
      mrun[vi] = mn;
#pragma unroll
      for (int nt = 0; nt < 4; nt++) acc[nt][vi] *= scale;
      Pl[wave][lg * 4 + vi][la]      = f2bf(p0);
      Pl[wave][lg * 4 + vi][16 + la] = f2bf(p1);
    }
    // ---- PV: out += P @ V ----
    bfx8 pf = *(const bfx8*)&Pl[wave][la][lg * 8];
#pragma unroll
    for (int nt = 0; nt < 4; nt++) {
      bfx8 vf = *(const bfx8*)&Vt[nt * 16 + la][lg * 8];
      acc[nt] = __builtin_amdgcn_mfma_f32_16x16x32_bf16(pf, vf, acc[nt], 0, 0, 0);
    }
    __syncthreads();
  }

  unsigned short* ob = att + ((size_t)(b * SS + qrow)) * DM + h * DK;
#pragma unroll
  for (int vi = 0; vi < 4; vi++) {
    const float inv = 1.f / lrun[vi];
#pragma unroll
    for (int nt = 0; nt < 4; nt++) {
      const float o = acc[nt][vi] * inv;
      ob[(size_t)(lg * 4 + vi) * DM + nt * 16 + la] = f2bf(o);
    }
  }
}

// ---------------------------------------------------------------------------
extern "C" void kernel_launch(void* const* d_in, const int* in_sizes, int n_in,
                              void* d_out, int out_size, void* d_ws, size_t ws_size,
                              hipStream_t stream) {
  const float* x    = (const float*)d_in[0];
  const float* wq   = (const float*)d_in[1];
  const float* bq   = (const float*)d_in[2];
  const float* wk   = (const float*)d_in[3];
  const float* bk   = (const float*)d_in[4];
  const float* wv   = (const float*)d_in[5];
  const float* bv   = (const float*)d_in[6];
  const float* wo   = (const float*)d_in[7];
  const float* bo   = (const float*)d_in[8];
  const float* w1   = (const float*)d_in[9];
  const float* b1   = (const float*)d_in[10];
  const float* w2   = (const float*)d_in[11];
  const float* b2   = (const float*)d_in[12];
  const float* ln1g = (const float*)d_in[13];
  const float* ln1b = (const float*)d_in[14];
  const float* ln2g = (const float*)d_in[15];
  const float* ln2b = (const float*)d_in[16];
  float* out = (float*)d_out;

  char* w = (char*)d_ws;
  const size_t MB = 1024ull * 1024ull;
  unsigned short* wqt = (unsigned short*)(w + 0 * MB);    // [1024][1024]
  unsigned short* wkt = (unsigned short*)(w + 2 * MB);
  unsigned short* wvt = (unsigned short*)(w + 4 * MB);
  unsigned short* wot = (unsigned short*)(w + 6 * MB);
  unsigned short* w1t = (unsigned short*)(w + 8 * MB);    // [4096][1024]
  unsigned short* w2t = (unsigned short*)(w + 16 * MB);   // [1024][4096]
  float*          x2  = (float*)         (w + 24 * MB);   // [8192][1024] f32
  unsigned short* hb  = (unsigned short*)(w + 56 * MB);   // [8192][1024] (h, then h2)
  unsigned short* qb  = (unsigned short*)(w + 72 * MB);
  unsigned short* kb  = (unsigned short*)(w + 88 * MB);
  unsigned short* vb2 = (unsigned short*)(w + 104 * MB);
  unsigned short* atb = (unsigned short*)(w + 120 * MB);
  unsigned short* ffb = (unsigned short*)(w + 72 * MB);   // [8192][4096] overlays q/k/v/att

  // 1) weight transposes (f32 -> bf16 W^T)
  k_transpose<<<dim3(32, 32),  256, 0, stream>>>(wq, wqt, 1024, 1024);
  k_transpose<<<dim3(32, 32),  256, 0, stream>>>(wk, wkt, 1024, 1024);
  k_transpose<<<dim3(32, 32),  256, 0, stream>>>(wv, wvt, 1024, 1024);
  k_transpose<<<dim3(32, 32),  256, 0, stream>>>(wo, wot, 1024, 1024);
  k_transpose<<<dim3(128, 32), 256, 0, stream>>>(w1, w1t, 1024, 4096);
  k_transpose<<<dim3(32, 128), 256, 0, stream>>>(w2, w2t, 4096, 1024);

  // 2) LN1: x -> h (bf16)
  k_layernorm<<<MROWS / 4, 256, 0, stream>>>(x, ln1g, ln1b, hb);

  // 3) QKV projections
  k_gemm_bt<0><<<dim3(8, 64), 256, 0, stream>>>(hb, wqt, bq, nullptr, qb,  MROWS, DM, DM);
  k_gemm_bt<0><<<dim3(8, 64), 256, 0, stream>>>(hb, wkt, bk, nullptr, kb,  MROWS, DM, DM);
  k_gemm_bt<0><<<dim3(8, 64), 256, 0, stream>>>(hb, wvt, bv, nullptr, vb2, MROWS, DM, DM);

  // 4) causal flash attention
  k_attn<<<dim3(SS / 64, NH, NB), 256, 0, stream>>>(qb, kb, vb2, atb);

  // 5) O projection + residual (f32 x2)
  k_gemm_bt<1><<<dim3(8, 64), 256, 0, stream>>>(atb, wot, bo, x, x2, MROWS, DM, DM);

  // 6) LN2: x2 -> h2 (bf16, reuse hb)
  k_layernorm<<<MROWS / 4, 256, 0, stream>>>(x2, ln2g, ln2b, hb);

  // 7) FF1 + GELU
  k_gemm_bt<2><<<dim3(32, 64), 256, 0, stream>>>(hb, w1t, b1, nullptr, ffb, MROWS, DFF, DM);

  // 8) FF2 + residual -> d_out (f32)
  k_gemm_bt<1><<<dim3(8, 64), 256, 0, stream>>>(ffb, w2t, b2, x2, out, MROWS, DM, DFF);
}

// Round 2
// 523.835 us; speedup vs baseline: 1.5186x; 1.5186x over previous
//
#include <hip/hip_runtime.h>
#include <hip/hip_bf16.h>

#define DM   1024
#define DFF  4096
#define NB   4
#define SS   2048
#define NH   16
#define DK   64
#define MROWS (NB*SS)   // 8192

typedef __attribute__((ext_vector_type(8))) short bfx8;
typedef __attribute__((ext_vector_type(4))) float fx4;
typedef unsigned int u32;
typedef unsigned short u16;

static __device__ __forceinline__ u16 f2bf(float f) {
  union { __hip_bfloat16 h; u16 u; } cv;
  cv.h = __float2bfloat16(f);
  return cv.u;
}
static __device__ __forceinline__ u32 pk2bf(float a, float b) {
  return (u32)f2bf(a) | ((u32)f2bf(b) << 16);
}

static __device__ __forceinline__ void async16(void* lds, const void* g) {
  typedef const __attribute__((address_space(1))) unsigned int* gp_t;
  typedef __attribute__((address_space(3))) unsigned int* lp_t;
  __builtin_amdgcn_global_load_lds((gp_t)g, (lp_t)lds, 16, 0, 0);
}

// ---------------- weight transpose + f32->bf16 cast: out[n][k] = in[k][n] ----
__global__ __launch_bounds__(256) void k_transpose(const float* __restrict__ in,
                                                   u16* __restrict__ out,
                                                   int K, int N) {
  __shared__ float t[32][33];
  const int n0 = blockIdx.x * 32, k0 = blockIdx.y * 32;
  const int tx = threadIdx.x & 31, ty = threadIdx.x >> 5;  // 32 x 8
#pragma unroll
  for (int j = 0; j < 4; j++)
    t[ty + j * 8][tx] = in[(size_t)(k0 + ty + j * 8) * N + n0 + tx];
  __syncthreads();
#pragma unroll
  for (int j = 0; j < 4; j++)
    out[(size_t)(n0 + ty + j * 8) * K + k0 + tx] = f2bf(t[tx][ty + j * 8]);
}

// ---------------- layernorm: f32 in -> bf16 out, one wave per row ----------
__global__ __launch_bounds__(256) void k_layernorm(const float* __restrict__ x,
                                                   const float* __restrict__ g,
                                                   const float* __restrict__ b,
                                                   u16* __restrict__ out) {
  const int row  = blockIdx.x * 4 + (threadIdx.x >> 6);
  const int lane = threadIdx.x & 63;
  const float* xr = x + (size_t)row * DM;
  float4 vb[4];
  float s = 0.f, s2 = 0.f;
#pragma unroll
  for (int j = 0; j < 4; j++) {
    float4 v = *(const float4*)(xr + j * 256 + lane * 4);
    vb[j] = v;
    s  += v.x + v.y + v.z + v.w;
    s2 += v.x * v.x + v.y * v.y + v.z * v.z + v.w * v.w;
  }
#pragma unroll
  for (int off = 1; off < 64; off <<= 1) {
    s  += __shfl_xor(s,  off);
    s2 += __shfl_xor(s2, off);
  }
  const float mu   = s * (1.f / DM);
  const float var  = s2 * (1.f / DM) - mu * mu;
  const float rstd = rsqrtf(var + 1e-5f);
  u16* orow = out + (size_t)row * DM;
#pragma unroll
  for (int j = 0; j < 4; j++) {
    const int col = j * 256 + lane * 4;
    uint2 o;
    o.x = pk2bf((vb[j].x - mu) * rstd * g[col + 0] + b[col + 0],
                (vb[j].y - mu) * rstd * g[col + 1] + b[col + 1]);
    o.y = pk2bf((vb[j].z - mu) * rstd * g[col + 2] + b[col + 2],
                (vb[j].w - mu) * rstd * g[col + 3] + b[col + 3]);
    *(uint2*)(orow + col) = o;
  }
}

// ---------------- GEMM: C[M,N] = A[M,K](bf16) @ BT[N,K](bf16)^T + bias -----
// EPI: 0 = bf16 out, 1 = f32 out (+res), 2 = bf16 gelu out, 3 = bf16 V^T out
template <int EPI>
__global__ __launch_bounds__(256) void k_gemm_bt(const u16* __restrict__ A,
                                                 const u16* __restrict__ BT,
                                                 const float* __restrict__ bias,
                                                 const float* __restrict__ res,
                                                 void* __restrict__ outp,
                                                 int M, int N, int K) {
  __shared__ u16 Al[128 * 32];
  __shared__ u16 Bl[128 * 32];
  const int tid = threadIdx.x, wave = tid >> 6, lane = tid & 63;
  // XCD-aware chunked swizzle (nwg % 8 == 0 for all our launches)
  const int nwg = gridDim.x * gridDim.y;
  const int bid = blockIdx.y * gridDim.x + blockIdx.x;
  const int swz = (bid & 7) * (nwg >> 3) + (bid >> 3);
  const int m0 = (swz / gridDim.x) * 128, n0 = (swz % gridDim.x) * 128;
  const int wm = (wave >> 1) * 64, wn = (wave & 1) * 64;
  const int la = lane & 15, lg = lane >> 4;
  fx4 acc[4][4];
#pragma unroll
  for (int i = 0; i < 4; i++)
#pragma unroll
    for (int j = 0; j < 4; j++) acc[i][j] = fx4{0.f, 0.f, 0.f, 0.f};

  const u16* ga = A  + (size_t)(m0 + wave * 32 + (lane >> 2)) * K + (lane & 3) * 8;
  const u16* gb = BT + (size_t)(n0 + wave * 32 + (lane >> 2)) * K + (lane & 3) * 8;
  char* lA = (char*)Al + wave * 2048;
  char* lB = (char*)Bl + wave * 2048;

  for (int k0 = 0; k0 < K; k0 += 32) {
    async16(lA,        ga + k0);
    async16(lA + 1024, ga + 16 * (size_t)K + k0);
    async16(lB,        gb + k0);
    async16(lB + 1024, gb + 16 * (size_t)K + k0);
    __syncthreads();
    bfx8 av[4], bv[4];
#pragma unroll
    for (int mt = 0; mt < 4; mt++)
      av[mt] = *(const bfx8*)((const char*)Al + (wm + mt * 16 + la) * 64 + lg * 16);
#pragma unroll
    for (int nt = 0; nt < 4; nt++)
      bv[nt] = *(const bfx8*)((const char*)Bl + (wn + nt * 16 + la) * 64 + lg * 16);
#pragma unroll
    for (int mt = 0; mt < 4; mt++)
#pragma unroll
      for (int nt = 0; nt < 4; nt++)
        acc[mt][nt] = __builtin_amdgcn_mfma_f32_16x16x32_bf16(av[mt], bv[nt], acc[mt][nt], 0, 0, 0);
    __syncthreads();
  }

#pragma unroll
  for (int nt = 0; nt < 4; nt++) {
    const int n = n0 + wn + nt * 16 + la;
    const float bs = bias[n];
    if constexpr (EPI == 3) {
      // write V^T: out[((b*NH+h)*DK+d)*SS + s], s = m & 2047
#pragma unroll
      for (int mt = 0; mt < 4; mt++) {
        const int m = m0 + wm + mt * 16 + (lane >> 4) * 4;
        const int bb = m >> 11, s = m & 2047;
        const int hh = n >> 6, d = n & 63;
        u16* vp = (u16*)outp + (((size_t)bb * NH + hh) * DK + d) * SS + s;
        uint2 o;
        o.x = pk2bf(acc[mt][nt][0] + bs, acc[mt][nt][1] + bs);
        o.y = pk2bf(acc[mt][nt][2] + bs, acc[mt][nt][3] + bs);
        *(uint2*)vp = o;
      }
    } else {
#pragma unroll
      for (int mt = 0; mt < 4; mt++) {
#pragma unroll
        for (int vv = 0; vv < 4; vv++) {
          const int m = m0 + wm + mt * 16 + lg * 4 + vv;
          const float val = acc[mt][nt][vv] + bs;
          const size_t idx = (size_t)m * N + n;
          if constexpr (EPI == 1) {
            ((float*)outp)[idx] = res[idx] + val;
          } else if constexpr (EPI == 2) {
            const float gl = 0.5f * val * (1.f + erff(val * 0.70710678118f));
            ((u16*)outp)[idx] = f2bf(gl);
          } else {
            ((u16*)outp)[idx] = f2bf(val);
          }
        }
      }
    }
  }
}

// ---------------- causal flash attention, swapped-QK^T, bf16 MFMA ----------
// grid (16,16,4) swizzled; block 256 = 4 waves; per wave 32 q-rows; KV chunk 128.
// K LDS [128 kv][64 d] slot-swizzled (^row&7); V^T LDS [64 d][128 s] (^row&15).
__global__ __launch_bounds__(256) void k_attn(const u16* __restrict__ q,
                                              const u16* __restrict__ k,
                                              const u16* __restrict__ vt,
                                              u16* __restrict__ att) {
  __shared__ u16 Kl[128 * 64];
  __shared__ u16 Vl[64 * 128];
  // XCD swizzle: all 16 q-blocks of one (b,h) land on one XCD's L2
  const int nwg = gridDim.x * gridDim.y * gridDim.z;  // 1024
  const int bid = (blockIdx.z * gridDim.y + blockIdx.y) * gridDim.x + blockIdx.x;
  const int L = (bid & 7) * (nwg >> 3) + (bid >> 3);
  const int bq = (SS / 128 - 1) - (L & 15);  // reversed: heavy blocks first
  const int h  = (L >> 4) & (NH - 1);
  const int b  = L >> 8;

  const int tid = threadIdx.x, wv = tid >> 6, lane = tid & 63;
  const int la = lane & 15, lg = lane >> 4;
  const int q0 = bq * 128;
  const int bh = b * NH + h;

  // Q fragments (B-operand): lane holds Q[q=qt*16+la][d = f*32 + lg*8 + j]
  bfx8 qf[2][2];
#pragma unroll
  for (int qt = 0; qt < 2; qt++) {
    const u16* qp = q + (size_t)(b * SS + q0 + wv * 32 + qt * 16 + la) * DM + h * DK + lg * 8;
#pragma unroll
    for (int f = 0; f < 2; f++) qf[qt][f] = *(const bfx8*)(qp + f * 32);
  }

  fx4 acc[2][4];
#pragma unroll
  for (int qt = 0; qt < 2; qt++)
#pragma unroll
    for (int dt = 0; dt < 4; dt++) acc[qt][dt] = fx4{0.f, 0.f, 0.f, 0.f};
  float mold[2] = {-1e30f, -1e30f}, lsum[2] = {0.f, 0.f};

  // staging lane constants (pre-swizzled global source, linear LDS dest)
  const int krow = lane >> 3;                        // 0..7
  const int kcol = (lane & 7) ^ krow;                // logical 16B slot
  const u16* kg0 = k + (size_t)(b * SS + wv * 32 + krow) * DM + h * DK + kcol * 8;
  const int vrow = lane >> 4;                        // 0..3
  const u16* vg0 = vt + (size_t)(bh * DK + wv * 16 + vrow) * SS;
  char* kbase = (char*)Kl + wv * 4096;
  char* vbase = (char*)Vl + wv * 4096;

  const float c1 = 0.18033688f;  // 0.125 * log2(e)

  for (int ch = 0; ch <= bq; ch++) {
    const int c0 = ch * 128;
#pragma unroll
    for (int i = 0; i < 4; i++)
      async16(kbase + i * 1024, kg0 + (size_t)(c0 + i * 8) * DM);
#pragma unroll
    for (int i = 0; i < 4; i++) {
      const int vcol = (lane & 15) ^ (i * 4 + vrow);
      async16(vbase + i * 1024, vg0 + (size_t)(i * 4) * SS + c0 + vcol * 8);
    }
    __syncthreads();
    const bool diag = (ch == bq);

#pragma unroll
    for (int sub = 0; sub < 2; sub++) {
      // ---- S^T = K @ Q^T : lane holds S^T[kv=t*16+lg*4+r][q=qt*16+la] ----
      fx4 st[2][4];
#pragma unroll
      for (int t = 0; t < 4; t++) {
        const char* kr = (const char*)Kl + (size_t)(sub * 64 + t * 16 + la) * 128;
        const int sw = la & 7;
        bfx8 kf0 = *(const bfx8*)(kr + ((0 + lg) ^ sw) * 16);
        bfx8 kf1 = *(const bfx8*)(kr + ((4 + lg) ^ sw) * 16);
#pragma unroll
        for (int qt = 0; qt < 2; qt++) {
          fx4 z = fx4{0.f, 0.f, 0.f, 0.f};
          z = __builtin_amdgcn_mfma_f32_16x16x32_bf16(kf0, qf[qt][0], z, 0, 0, 0);
          z = __builtin_amdgcn_mfma_f32_16x16x32_bf16(kf1, qf[qt][1], z, 0, 0, 0);
          st[qt][t] = z;
        }
      }
      if (diag) {
#pragma unroll
        for (int qt = 0; qt < 2; qt++) {
          const int qir = wv * 32 + qt * 16 + la;
#pragma unroll
          for (int t = 0; t < 4; t++)
#pragma unroll
            for (int r = 0; r < 4; r++)
              if (sub * 64 + t * 16 + lg * 4 + r > qir) st[qt][t][r] = -1e30f;
        }
      }
      // ---- online softmax (per lane: one q-row per qt) ----
      u32 W[2][4][2];
#pragma unroll
      for (int qt = 0; qt < 2; qt++) {
        float mx = fmaxf(fmaxf(st[qt][0][0], st[qt][0][1]), fmaxf(st[qt][0][2], st[qt][0][3]));
#pragma unroll
        for (int t = 1; t < 4; t++) {
          mx = fmaxf(mx, fmaxf(fmaxf(st[qt][t][0], st[qt][t][1]), fmaxf(st[qt][t][2], st[qt][t][3])));
        }
        mx = fmaxf(mx, __shfl_xor(mx, 16));
        mx = fmaxf(mx, __shfl_xor(mx, 32));
        const float mnew = fmaxf(mold[qt], mx * c1);
        const float scale = exp2f(mold[qt] - mnew);
        mold[qt] = mnew;
        float ps = 0.f;
#pragma unroll
        for (int t = 0; t < 4; t++)
#pragma unroll
          for (int r = 0; r < 4; r++) {
            const float p = exp2f(fmaf(st[qt][t][r], c1, -mnew));
            st[qt][t][r] = p;
            ps += p;
          }
        ps += __shfl_xor(ps, 16);
        ps += __shfl_xor(ps, 32);
        lsum[qt] = lsum[qt] * scale + ps;
#pragma unroll
        for (int dt = 0; dt < 4; dt++) {
          acc[qt][dt][0] *= scale; acc[qt][dt][1] *= scale;
          acc[qt][dt][2] *= scale; acc[qt][dt][3] *= scale;
        }
#pragma unroll
        for (int t = 0; t < 4; t++) {
          W[qt][t][0] = pk2bf(st[qt][t][0], st[qt][t][1]);
          W[qt][t][1] = pk2bf(st[qt][t][2], st[qt][t][3]);
        }
      }
      // ---- PV: O^T += V^T @ P^T.  Rebuild P B-frag in-register via shfl ----
      const int sLo = la + ((lg & 1) << 5);
      const int sHi = sLo + 16;
      const bool tHi = (lg >> 1) & 1;
#pragma unroll
      for (int f = 0; f < 2; f++) {
        bfx8 pf[2];
#pragma unroll
        for (int qt = 0; qt < 2; qt++) {
          const u32 a0 = __shfl(W[qt][2 * f][0], sLo), b0 = __shfl(W[qt][2 * f + 1][0], sLo);
          const u32 a1 = __shfl(W[qt][2 * f][1], sLo), b1 = __shfl(W[qt][2 * f + 1][1], sLo);
          const u32 a2 = __shfl(W[qt][2 * f][0], sHi), b2 = __shfl(W[qt][2 * f + 1][0], sHi);
          const u32 a3 = __shfl(W[qt][2 * f][1], sHi), b3 = __shfl(W[qt][2 * f + 1][1], sHi);
          union { u32 u[4]; bfx8 v; } pu;
          pu.u[0] = tHi ? b0 : a0;
          pu.u[1] = tHi ? b1 : a1;
          pu.u[2] = tHi ? b2 : a2;
          pu.u[3] = tHi ? b3 : a3;
          pf[qt] = pu.v;
        }
#pragma unroll
        for (int dt = 0; dt < 4; dt++) {
          const int row = dt * 16 + la;
          bfx8 vf = *(const bfx8*)((const char*)Vl + (size_t)row * 256 +
                                   (((sub << 3) + (f << 2) + lg) ^ la) * 16);
          acc[0][dt] = __builtin_amdgcn_mfma_f32_16x16x32_bf16(vf, pf[0], acc[0][dt], 0, 0, 0);
          acc[1][dt] = __builtin_amdgcn_mfma_f32_16x16x32_bf16(vf, pf[1], acc[1][dt], 0, 0, 0);
        }
      }
    }
    __syncthreads();
  }

  // ---- write O (lane holds O^T[d=dt*16+lg*4+r][q=qt*16+la]) ----
#pragma unroll
  for (int qt = 0; qt < 2; qt++) {
    const float inv = 1.f / lsum[qt];
    u16* ob = att + (size_t)(b * SS + q0 + wv * 32 + qt * 16 + la) * DM + h * DK + lg * 4;
#pragma unroll
    for (int dt = 0; dt < 4; dt++) {
      uint2 o;
      o.x = pk2bf(acc[qt][dt][0] * inv, acc[qt][dt][1] * inv);
      o.y = pk2bf(acc[qt][dt][2] * inv, acc[qt][dt][3] * inv);
      *(uint2*)(ob + dt * 16) = o;
    }
  }
}

// ---------------------------------------------------------------------------
extern "C" void kernel_launch(void* const* d_in, const int* in_sizes, int n_in,
                              void* d_out, int out_size, void* d_ws, size_t ws_size,
                              hipStream_t stream) {
  const float* x    = (const float*)d_in[0];
  const float* wq   = (const float*)d_in[1];
  const float* bq   = (const float*)d_in[2];
  const float* wk   = (const float*)d_in[3];
  const float* bk   = (const float*)d_in[4];
  const float* wv   = (const float*)d_in[5];
  const float* bv   = (const float*)d_in[6];
  const float* wo   = (const float*)d_in[7];
  const float* bo   = (const float*)d_in[8];
  const float* w1   = (const float*)d_in[9];
  const float* b1   = (const float*)d_in[10];
  const float* w2   = (const float*)d_in[11];
  const float* b2   = (const float*)d_in[12];
  const float* ln1g = (const float*)d_in[13];
  const float* ln1b = (const float*)d_in[14];
  const float* ln2g = (const float*)d_in[15];
  const float* ln2b = (const float*)d_in[16];
  float* out = (float*)d_out;

  char* w = (char*)d_ws;
  const size_t MB = 1024ull * 1024ull;
  u16*   wqt = (u16*)(w + 0 * MB);    // [1024][1024] bf16
  u16*   wkt = (u16*)(w + 2 * MB);
  u16*   wvt = (u16*)(w + 4 * MB);
  u16*   wot = (u16*)(w + 6 * MB);
  u16*   w1t = (u16*)(w + 8 * MB);    // [4096][1024]
  u16*   w2t = (u16*)(w + 16 * MB);   // [1024][4096]
  float* x2  = (float*)(w + 24 * MB); // [8192][1024] f32
  u16*   hb  = (u16*)(w + 56 * MB);   // [8192][1024] (h, then h2)
  u16*   qb  = (u16*)(w + 72 * MB);   // [8192][1024]
  u16*   kb  = (u16*)(w + 88 * MB);   // [8192][1024]
  u16*   vtb = (u16*)(w + 104 * MB);  // [4][16][64][2048] V^T per head
  u16*   atb = (u16*)(w + 120 * MB);  // [8192][1024]
  u16*   ffb = (u16*)(w + 72 * MB);   // [8192][4096] overlays q/k/vt/att

  // 1) weight transposes (f32 -> bf16 W^T)
  k_transpose<<<dim3(32, 32),  256, 0, stream>>>(wq, wqt, 1024, 1024);
  k_transpose<<<dim3(32, 32),  256, 0, stream>>>(wk, wkt, 1024, 1024);
  k_transpose<<<dim3(32, 32),  256, 0, stream>>>(wv, wvt, 1024, 1024);
  k_transpose<<<dim3(32, 32),  256, 0, stream>>>(wo, wot, 1024, 1024);
  k_transpose<<<dim3(128, 32), 256, 0, stream>>>(w1, w1t, 1024, 4096);
  k_transpose<<<dim3(32, 128), 256, 0, stream>>>(w2, w2t, 4096, 1024);

  // 2) LN1: x -> h (bf16)
  k_layernorm<<<MROWS / 4, 256, 0, stream>>>(x, ln1g, ln1b, hb);

  // 3) QKV projections (V written per-head-transposed)
  k_gemm_bt<0><<<dim3(8, 64), 256, 0, stream>>>(hb, wqt, bq, nullptr, qb,  MROWS, DM, DM);
  k_gemm_bt<0><<<dim3(8, 64), 256, 0, stream>>>(hb, wkt, bk, nullptr, kb,  MROWS, DM, DM);
  k_gemm_bt<3><<<dim3(8, 64), 256, 0, stream>>>(hb, wvt, bv, nullptr, vtb, MROWS, DM, DM);

  // 4) causal flash attention (swapped QK^T)
  k_attn<<<dim3(SS / 128, NH, NB), 256, 0, stream>>>(qb, kb, vtb, atb);

  // 5) O projection + residual (f32 x2)
  k_gemm_bt<1><<<dim3(8, 64), 256, 0, stream>>>(atb, wot, bo, x, x2, MROWS, DM, DM);

  // 6) LN2: x2 -> h2 (bf16, reuse hb)
  k_layernorm<<<MROWS / 4, 256, 0, stream>>>(x2, ln2g, ln2b, hb);

  // 7) FF1 + GELU
  k_gemm_bt<2><<<dim3(32, 64), 256, 0, stream>>>(hb, w1t, b1, nullptr, ffb, MROWS, DFF, DM);

  // 8) FF2 + residual -> d_out (f32)
  k_gemm_bt<1><<<dim3(8, 64), 256, 0, stream>>>(ffb, w2t, b2, x2, out, MROWS, DM, DFF);
}

// Round 4
// 504.869 us; speedup vs baseline: 1.5757x; 1.0376x over previous
//
#include <hip/hip_runtime.h>
#include <hip/hip_bf16.h>

#define DM   1024
#define DFF  4096
#define NB   4
#define SS   2048
#define NH   16
#define DK   64
#define MROWS (NB*SS)   // 8192

typedef __attribute__((ext_vector_type(8))) short bfx8;
typedef __attribute__((ext_vector_type(4))) float fx4;
typedef unsigned int u32;
typedef unsigned short u16;

static __device__ __forceinline__ u16 f2bf(float f) {
  union { __hip_bfloat16 h; u16 u; } cv;
  cv.h = __float2bfloat16(f);
  return cv.u;
}
static __device__ __forceinline__ u32 pk2bf(float a, float b) {
  return (u32)f2bf(a) | ((u32)f2bf(b) << 16);
}

static __device__ __forceinline__ void async16(void* lds, const void* g) {
  typedef const __attribute__((address_space(1))) unsigned int* gp_t;
  typedef __attribute__((address_space(3))) unsigned int* lp_t;
  __builtin_amdgcn_global_load_lds((gp_t)g, (lp_t)lds, 16, 0, 0);
}

// ---------------- weight transpose + f32->bf16 cast: out[n][k] = in[k][n] ----
__global__ __launch_bounds__(256) void k_transpose(const float* __restrict__ in,
                                                   u16* __restrict__ out,
                                                   int K, int N) {
  __shared__ float t[32][33];
  const int n0 = blockIdx.x * 32, k0 = blockIdx.y * 32;
  const int tx = threadIdx.x & 31, ty = threadIdx.x >> 5;  // 32 x 8
#pragma unroll
  for (int j = 0; j < 4; j++)
    t[ty + j * 8][tx] = in[(size_t)(k0 + ty + j * 8) * N + n0 + tx];
  __syncthreads();
#pragma unroll
  for (int j = 0; j < 4; j++)
    out[(size_t)(n0 + ty + j * 8) * K + k0 + tx] = f2bf(t[tx][ty + j * 8]);
}

// ---------------- layernorm: f32 in -> bf16 out, one wave per row ----------
__global__ __launch_bounds__(256) void k_layernorm(const float* __restrict__ x,
                                                   const float* __restrict__ g,
                                                   const float* __restrict__ b,
                                                   u16* __restrict__ out) {
  const int row  = blockIdx.x * 4 + (threadIdx.x >> 6);
  const int lane = threadIdx.x & 63;
  const float* xr = x + (size_t)row * DM;
  float4 vb[4];
  float s = 0.f, s2 = 0.f;
#pragma unroll
  for (int j = 0; j < 4; j++) {
    float4 v = *(const float4*)(xr + j * 256 + lane * 4);
    vb[j] = v;
    s  += v.x + v.y + v.z + v.w;
    s2 += v.x * v.x + v.y * v.y + v.z * v.z + v.w * v.w;
  }
#pragma unroll
  for (int off = 1; off < 64; off <<= 1) {
    s  += __shfl_xor(s,  off);
    s2 += __shfl_xor(s2, off);
  }
  const float mu   = s * (1.f / DM);
  const float var  = s2 * (1.f / DM) - mu * mu;
  const float rstd = rsqrtf(var + 1e-5f);
  u16* orow = out + (size_t)row * DM;
#pragma unroll
  for (int j = 0; j < 4; j++) {
    const int col = j * 256 + lane * 4;
    uint2 o;
    o.x = pk2bf((vb[j].x - mu) * rstd * g[col + 0] + b[col + 0],
                (vb[j].y - mu) * rstd * g[col + 1] + b[col + 1]);
    o.y = pk2bf((vb[j].z - mu) * rstd * g[col + 2] + b[col + 2],
                (vb[j].w - mu) * rstd * g[col + 3] + b[col + 3]);
    *(uint2*)(orow + col) = o;
  }
}

// ---------------- GEMM: C[M,N] = A[M,K](bf16) @ BT[N,K](bf16)^T + bias -----
// EPI: 1 = f32 out (+res), 2 = bf16 gelu out, 4 = fused QKV (Q,K row-major; V per-head-T)
template <int EPI>
__global__ __launch_bounds__(256) void k_gemm_bt(const u16* __restrict__ A,
                                                 const u16* __restrict__ BT,
                                                 const float* __restrict__ bias0,
                                                 const float* __restrict__ bias1,
                                                 const float* __restrict__ bias2,
                                                 const float* __restrict__ res,
                                                 void* __restrict__ outp,
                                                 int M, int N, int K) {
  __shared__ u16 Al[128 * 32];
  __shared__ u16 Bl[128 * 32];
  const int tid = threadIdx.x, wave = tid >> 6, lane = tid & 63;
  // XCD-aware chunked swizzle (nwg % 8 == 0 for all our launches)
  const int nwg = gridDim.x * gridDim.y;
  const int bid = blockIdx.y * gridDim.x + blockIdx.x;
  const int swz = (bid & 7) * (nwg >> 3) + (bid >> 3);
  const int m0 = (swz / gridDim.x) * 128, n0 = (swz % gridDim.x) * 128;
  const int wm = (wave >> 1) * 64, wn = (wave & 1) * 64;
  const int la = lane & 15, lg = lane >> 4;
  fx4 acc[4][4];
#pragma unroll
  for (int i = 0; i < 4; i++)
#pragma unroll
    for (int j = 0; j < 4; j++) acc[i][j] = fx4{0.f, 0.f, 0.f, 0.f};

  const u16* ga = A  + (size_t)(m0 + wave * 32 + (lane >> 2)) * K + (lane & 3) * 8;
  const u16* gb = BT + (size_t)(n0 + wave * 32 + (lane >> 2)) * K + (lane & 3) * 8;
  char* lA = (char*)Al + wave * 2048;
  char* lB = (char*)Bl + wave * 2048;

  for (int k0 = 0; k0 < K; k0 += 32) {
    async16(lA,        ga + k0);
    async16(lA + 1024, ga + 16 * (size_t)K + k0);
    async16(lB,        gb + k0);
    async16(lB + 1024, gb + 16 * (size_t)K + k0);
    __syncthreads();
    bfx8 av[4], bv[4];
#pragma unroll
    for (int mt = 0; mt < 4; mt++)
      av[mt] = *(const bfx8*)((const char*)Al + (wm + mt * 16 + la) * 64 + lg * 16);
#pragma unroll
    for (int nt = 0; nt < 4; nt++)
      bv[nt] = *(const bfx8*)((const char*)Bl + (wn + nt * 16 + la) * 64 + lg * 16);
    __builtin_amdgcn_s_setprio(1);
#pragma unroll
    for (int mt = 0; mt < 4; mt++)
#pragma unroll
      for (int nt = 0; nt < 4; nt++)
        acc[mt][nt] = __builtin_amdgcn_mfma_f32_16x16x32_bf16(av[mt], bv[nt], acc[mt][nt], 0, 0, 0);
    __builtin_amdgcn_s_setprio(0);
    __syncthreads();
  }

  if constexpr (EPI == 4) {
    const int reg = n0 >> 10;  // 0=Q, 1=K, 2=V (block-uniform; n0 multiple of 128)
    const float* bp = (reg == 0) ? bias0 : (reg == 1) ? bias1 : bias2;
#pragma unroll
    for (int nt = 0; nt < 4; nt++) {
      const int n  = n0 + wn + nt * 16 + la;
      const int nl = n & 1023;
      const float bs = bp[nl];
      if (reg < 2) {
        u16* base = (u16*)outp + (size_t)reg * (8u * 1024 * 1024);
#pragma unroll
        for (int mt = 0; mt < 4; mt++)
#pragma unroll
          for (int vv = 0; vv < 4; vv++) {
            const int m = m0 + wm + mt * 16 + lg * 4 + vv;
            base[(size_t)m * 1024 + nl] = f2bf(acc[mt][nt][vv] + bs);
          }
      } else {
        const int hh = nl >> 6, d = nl & 63;
#pragma unroll
        for (int mt = 0; mt < 4; mt++) {
          const int m = m0 + wm + mt * 16 + lg * 4;
          const int bb = m >> 11, s = m & 2047;
          u16* vp = (u16*)outp + 16u * 1024 * 1024 +
                    (((size_t)bb * NH + hh) * DK + d) * SS + s;
          uint2 o;
          o.x = pk2bf(acc[mt][nt][0] + bs, acc[mt][nt][1] + bs);
          o.y = pk2bf(acc[mt][nt][2] + bs, acc[mt][nt][3] + bs);
          *(uint2*)vp = o;
        }
      }
    }
  } else {
#pragma unroll
    for (int nt = 0; nt < 4; nt++) {
      const int n = n0 + wn + nt * 16 + la;
      const float bs = bias0[n];
#pragma unroll
      for (int mt = 0; mt < 4; mt++) {
#pragma unroll
        for (int vv = 0; vv < 4; vv++) {
          const int m = m0 + wm + mt * 16 + lg * 4 + vv;
          const float val = acc[mt][nt][vv] + bs;
          const size_t idx = (size_t)m * N + n;
          if constexpr (EPI == 1) {
            ((float*)outp)[idx] = res[idx] + val;
          } else {
            const float gl = 0.5f * val * (1.f + erff(val * 0.70710678118f));
            ((u16*)outp)[idx] = f2bf(gl);
          }
        }
      }
    }
  }
}

// ---------------- causal flash attention, swapped-QK^T, bf16 MFMA ----------
// grid (16,16,4) swizzled; block 256 = 4 waves; per wave 32 q-rows.
// KV chunk 64, DOUBLE-buffered; one barrier per chunk; prefetch overlaps compute.
// K LDS [64 kv][64 d] slot-swizzled (^row&7); V^T LDS [64 d][64 s] (^row&7).
__global__ __launch_bounds__(256) void k_attn(const u16* __restrict__ q,
                                              const u16* __restrict__ k,
                                              const u16* __restrict__ vt,
                                              u16* __restrict__ att) {
  __shared__ u16 Kl[2 * 64 * 64];   // 16 KB (two 8 KB buffers)
  __shared__ u16 Vl[2 * 64 * 64];   // 16 KB
  // XCD swizzle: all 16 q-blocks of one (b,h) land on one XCD's L2
  const int nwg = gridDim.x * gridDim.y * gridDim.z;  // 1024
  const int bid = (blockIdx.z * gridDim.y + blockIdx.y) * gridDim.x + blockIdx.x;
  const int L = (bid & 7) * (nwg >> 3) + (bid >> 3);
  const int bq = (SS / 128 - 1) - (L & 15);  // reversed: heavy blocks first
  const int h  = (L >> 4) & (NH - 1);
  const int b  = L >> 8;

  const int tid = threadIdx.x, wv = tid >> 6, lane = tid & 63;
  const int la = lane & 15, lg = lane >> 4;
  const int q0 = bq * 128;
  const int bh = b * NH + h;

  // Q fragments (B-operand): lane holds Q[q=qt*16+la][d = f*32 + lg*8 + j]
  bfx8 qf[2][2];
#pragma unroll
  for (int qt = 0; qt < 2; qt++) {
    const u16* qp = q + (size_t)(b * SS + q0 + wv * 32 + qt * 16 + la) * DM + h * DK + lg * 8;
#pragma unroll
    for (int f = 0; f < 2; f++) qf[qt][f] = *(const bfx8*)(qp + f * 32);
  }

  fx4 acc[2][4];
#pragma unroll
  for (int qt = 0; qt < 2; qt++)
#pragma unroll
    for (int dt = 0; dt < 4; dt++) acc[qt][dt] = fx4{0.f, 0.f, 0.f, 0.f};
  float mold[2] = {-1e30f, -1e30f}, lsum[2] = {0.f, 0.f};

  // staging lane constants (pre-swizzled global source, linear LDS dest)
  // K: wave stages kv rows [wv*16, wv*16+16); 2 x async16 of 8 rows x 128B.
  const int krow = lane >> 3;                        // 0..7
  const int kcol = (lane & 7) ^ krow;                // logical 16B slot (8/row)
  const u16* kg0 = k + (size_t)(b * SS + wv * 16 + krow) * DM + h * DK + kcol * 8;
  // V^T: wave stages d rows [wv*16, wv*16+16); 2 x async16 of 8 rows x 128B.
  const int vrow = lane >> 3;                        // 0..7
  const int vcol = (lane & 7) ^ vrow;                // logical 16B slot (8/row)
  const u16* vg0 = vt + (size_t)(bh * DK + wv * 16 + vrow) * SS + vcol * 8;
  char* kq = (char*)Kl + wv * 2048;   // wave's quarter (16 rows x 128B)
  char* vq = (char*)Vl + wv * 2048;

  const float c1 = 0.18033688f;  // 0.125 * log2(e)
  const int nch = 2 * bq + 2;    // 64-wide chunks

  auto stage = [&](int buf, int c0) {
#pragma unroll
    for (int i = 0; i < 2; i++)
      async16(kq + buf * 8192 + i * 1024, kg0 + (size_t)(c0 + i * 8) * DM);
#pragma unroll
    for (int i = 0; i < 2; i++)
      async16(vq + buf * 8192 + i * 1024, vg0 + (size_t)(i * 8) * SS + c0);
  };

  stage(0, 0);
  int cur = 0;

  for (int ch = 0; ch < nch; ch++) {
    __syncthreads();                 // buf[cur] staged (drains own vmcnt) + prev reads done
    if (ch + 1 < nch) stage(cur ^ 1, (ch + 1) * 64);
    const int c0 = ch * 64;
    const bool msk = (ch >= nch - 2);
    const char* Kb = (const char*)Kl + cur * 8192;   // buffer stride = 64 rows x 128 B
    const char* Vb = (const char*)Vl + cur * 8192;

    // ---- S^T = K @ Q^T : lane holds S^T[kv=t*16+lg*4+r][q=qt*16+la] ----
    fx4 st[2][4];
    __builtin_amdgcn_s_setprio(1);
#pragma unroll
    for (int t = 0; t < 4; t++) {
      const char* kr = Kb + (size_t)(t * 16 + la) * 128;
      const int sw = la & 7;
      bfx8 kf0 = *(const bfx8*)(kr + ((0 + lg) ^ sw) * 16);
      bfx8 kf1 = *(const bfx8*)(kr + ((4 + lg) ^ sw) * 16);
#pragma unroll
      for (int qt = 0; qt < 2; qt++) {
        fx4 z = fx4{0.f, 0.f, 0.f, 0.f};
        z = __builtin_amdgcn_mfma_f32_16x16x32_bf16(kf0, qf[qt][0], z, 0, 0, 0);
        z = __builtin_amdgcn_mfma_f32_16x16x32_bf16(kf1, qf[qt][1], z, 0, 0, 0);
        st[qt][t] = z;
      }
    }
    __builtin_amdgcn_s_setprio(0);

    if (msk) {
#pragma unroll
      for (int qt = 0; qt < 2; qt++) {
        const int qir = q0 + wv * 32 + qt * 16 + la;
#pragma unroll
        for (int t = 0; t < 4; t++)
#pragma unroll
          for (int r = 0; r < 4; r++)
            if (c0 + t * 16 + lg * 4 + r > qir) st[qt][t][r] = -1e30f;
      }
    }

    // ---- online softmax with defer-max (THR = 8 in log2 domain) ----
    float mxs[2];
#pragma unroll
    for (int qt = 0; qt < 2; qt++) {
      float mx = fmaxf(fmaxf(st[qt][0][0], st[qt][0][1]), fmaxf(st[qt][0][2], st[qt][0][3]));
#pragma unroll
      for (int t = 1; t < 4; t++)
        mx = fmaxf(mx, fmaxf(fmaxf(st[qt][t][0], st[qt][t][1]), fmaxf(st[qt][t][2], st[qt][t][3])));
      mx = fmaxf(mx, __shfl_xor(mx, 16));
      mx = fmaxf(mx, __shfl_xor(mx, 32));
      mxs[qt] = mx * c1;
    }
    const bool defer = (mxs[0] <= mold[0] + 8.f) && (mxs[1] <= mold[1] + 8.f);
    if (!__all(defer)) {
#pragma unroll
      for (int qt = 0; qt < 2; qt++) {
        const float mnew  = fmaxf(mold[qt], mxs[qt]);
        const float scale = exp2f(mold[qt] - mnew);
        mold[qt] = mnew;
        lsum[qt] *= scale;
#pragma unroll
        for (int dt = 0; dt < 4; dt++) {
          acc[qt][dt][0] *= scale; acc[qt][dt][1] *= scale;
          acc[qt][dt][2] *= scale; acc[qt][dt][3] *= scale;
        }
      }
    }
    u32 W[2][4][2];
#pragma unroll
    for (int qt = 0; qt < 2; qt++) {
      float ps = 0.f;
#pragma unroll
      for (int t = 0; t < 4; t++) {
        float p0 = exp2f(fmaf(st[qt][t][0], c1, -mold[qt]));
        float p1 = exp2f(fmaf(st[qt][t][1], c1, -mold[qt]));
        float p2 = exp2f(fmaf(st[qt][t][2], c1, -mold[qt]));
        float p3 = exp2f(fmaf(st[qt][t][3], c1, -mold[qt]));
        ps += (p0 + p1) + (p2 + p3);
        W[qt][t][0] = pk2bf(p0, p1);
        W[qt][t][1] = pk2bf(p2, p3);
      }
      ps += __shfl_xor(ps, 16);
      ps += __shfl_xor(ps, 32);
      lsum[qt] += ps;
    }

    // ---- PV: O^T += V^T @ P^T.  Rebuild P B-frag in-register via shfl ----
    const int sLo = la + ((lg & 1) << 5);
    const int sHi = sLo + 16;
    const bool tHi = (lg >> 1) & 1;
#pragma unroll
    for (int f = 0; f < 2; f++) {
      bfx8 pf[2];
#pragma unroll
      for (int qt = 0; qt < 2; qt++) {
        const u32 a0 = __shfl(W[qt][2 * f][0], sLo), b0 = __shfl(W[qt][2 * f + 1][0], sLo);
        const u32 a1 = __shfl(W[qt][2 * f][1], sLo), b1 = __shfl(W[qt][2 * f + 1][1], sLo);
        const u32 a2 = __shfl(W[qt][2 * f][0], sHi), b2 = __shfl(W[qt][2 * f + 1][0], sHi);
        const u32 a3 = __shfl(W[qt][2 * f][1], sHi), b3 = __shfl(W[qt][2 * f + 1][1], sHi);
        union { u32 u[4]; bfx8 v; } pu;
        pu.u[0] = tHi ? b0 : a0;
        pu.u[1] = tHi ? b1 : a1;
        pu.u[2] = tHi ? b2 : a2;
        pu.u[3] = tHi ? b3 : a3;
        pf[qt] = pu.v;
      }
      __builtin_amdgcn_s_setprio(1);
#pragma unroll
      for (int dt = 0; dt < 4; dt++) {
        const int row = dt * 16 + la;
        bfx8 vf = *(const bfx8*)(Vb + (size_t)row * 128 +
                                 (((f << 2) + lg) ^ (la & 7)) * 16);
        acc[0][dt] = __builtin_amdgcn_mfma_f32_16x16x32_bf16(vf, pf[0], acc[0][dt], 0, 0, 0);
        acc[1][dt] = __builtin_amdgcn_mfma_f32_16x16x32_bf16(vf, pf[1], acc[1][dt], 0, 0, 0);
      }
      __builtin_amdgcn_s_setprio(0);
    }
    cur ^= 1;
  }

  // ---- write O (lane holds O^T[d=dt*16+lg*4+r][q=qt*16+la]) ----
#pragma unroll
  for (int qt = 0; qt < 2; qt++) {
    const float inv = 1.f / lsum[qt];
    u16* ob = att + (size_t)(b * SS + q0 + wv * 32 + qt * 16 + la) * DM + h * DK + lg * 4;
#pragma unroll
    for (int dt = 0; dt < 4; dt++) {
      uint2 o;
      o.x = pk2bf(acc[qt][dt][0] * inv, acc[qt][dt][1] * inv);
      o.y = pk2bf(acc[qt][dt][2] * inv, acc[qt][dt][3] * inv);
      *(uint2*)(ob + dt * 16) = o;
    }
  }
}

// ---------------------------------------------------------------------------
extern "C" void kernel_launch(void* const* d_in, const int* in_sizes, int n_in,
                              void* d_out, int out_size, void* d_ws, size_t ws_size,
                              hipStream_t stream) {
  const float* x    = (const float*)d_in[0];
  const float* wq   = (const float*)d_in[1];
  const float* bq   = (const float*)d_in[2];
  const float* wk   = (const float*)d_in[3];
  const float* bk   = (const float*)d_in[4];
  const float* wv   = (const float*)d_in[5];
  const float* bv   = (const float*)d_in[6];
  const float* wo   = (const float*)d_in[7];
  const float* bo   = (const float*)d_in[8];
  const float* w1   = (const float*)d_in[9];
  const float* b1   = (const float*)d_in[10];
  const float* w2   = (const float*)d_in[11];
  const float* b2   = (const float*)d_in[12];
  const float* ln1g = (const float*)d_in[13];
  const float* ln1b = (const float*)d_in[14];
  const float* ln2g = (const float*)d_in[15];
  const float* ln2b = (const float*)d_in[16];
  float* out = (float*)d_out;

  char* w = (char*)d_ws;
  const size_t MB = 1024ull * 1024ull;
  u16*   wqkv = (u16*)(w + 0 * MB);   // [3072][1024] bf16 (Q,K,V stacked)
  u16*   wot  = (u16*)(w + 6 * MB);   // [1024][1024]
  u16*   w1t  = (u16*)(w + 8 * MB);   // [4096][1024]
  u16*   w2t  = (u16*)(w + 16 * MB);  // [1024][4096]
  float* x2   = (float*)(w + 24 * MB);// [8192][1024] f32
  u16*   hb   = (u16*)(w + 56 * MB);  // [8192][1024] (h, then h2)
  u16*   qb   = (u16*)(w + 72 * MB);  // [8192][1024]  -- K at +8M u16, V^T at +16M u16
  u16*   kb   = (u16*)(w + 88 * MB);
  u16*   vtb  = (u16*)(w + 104 * MB); // [4][16][64][2048] V^T per head
  u16*   atb  = (u16*)(w + 120 * MB); // [8192][1024]
  u16*   ffb  = (u16*)(w + 72 * MB);  // [8192][4096] overlays q/k/vt/att

  // 1) weight transposes (f32 -> bf16 W^T); QKV stacked into one [3072][1024]
  k_transpose<<<dim3(32, 32),  256, 0, stream>>>(wq, wqkv,               1024, 1024);
  k_transpose<<<dim3(32, 32),  256, 0, stream>>>(wk, wqkv + 1024 * 1024, 1024, 1024);
  k_transpose<<<dim3(32, 32),  256, 0, stream>>>(wv, wqkv + 2048 * 1024, 1024, 1024);
  k_transpose<<<dim3(32, 32),  256, 0, stream>>>(wo, wot, 1024, 1024);
  k_transpose<<<dim3(128, 32), 256, 0, stream>>>(w1, w1t, 1024, 4096);
  k_transpose<<<dim3(32, 128), 256, 0, stream>>>(w2, w2t, 4096, 1024);

  // 2) LN1: x -> h (bf16)
  k_layernorm<<<MROWS / 4, 256, 0, stream>>>(x, ln1g, ln1b, hb);

  // 3) fused QKV projection (Q,K row-major bf16; V per-head-transposed)
  k_gemm_bt<4><<<dim3(24, 64), 256, 0, stream>>>(hb, wqkv, bq, bk, bv, nullptr, qb,
                                                 MROWS, 3 * DM, DM);

  // 4) causal flash attention (swapped QK^T, double-buffered KV)
  k_attn<<<dim3(SS / 128, NH, NB), 256, 0, stream>>>(qb, kb, vtb, atb);

  // 5) O projection + residual (f32 x2)
  k_gemm_bt<1><<<dim3(8, 64), 256, 0, stream>>>(atb, wot, bo, nullptr, nullptr, x, x2,
                                                MROWS, DM, DM);

  // 6) LN2: x2 -> h2 (bf16, reuse hb)
  k_layernorm<<<MROWS / 4, 256, 0, stream>>>(x2, ln2g, ln2b, hb);

  // 7) FF1 + GELU
  k_gemm_bt<2><<<dim3(32, 64), 256, 0, stream>>>(hb, w1t, b1, nullptr, nullptr, nullptr, ffb,
                                                 MROWS, DFF, DM);

  // 8) FF2 + residual -> d_out (f32)
  k_gemm_bt<1><<<dim3(8, 64), 256, 0, stream>>>(ffb, w2t, b2, nullptr, nullptr, x2, out,
                                                MROWS, DM, DFF);
}

// Round 5
// 405.741 us; speedup vs baseline: 1.9606x; 1.2443x over previous
//
#include <hip/hip_runtime.h>
#include <hip/hip_bf16.h>

#define DM   1024
#define DFF  4096
#define NB   4
#define SS   2048
#define NH   16
#define DK   64
#define MROWS (NB*SS)   // 8192

typedef __attribute__((ext_vector_type(8))) short bfx8;
typedef __attribute__((ext_vector_type(4))) float fx4;
typedef unsigned int u32;
typedef unsigned short u16;

static __device__ __forceinline__ u16 f2bf(float f) {
  union { __hip_bfloat16 h; u16 u; } cv;
  cv.h = __float2bfloat16(f);
  return cv.u;
}
static __device__ __forceinline__ u32 pk2bf(float a, float b) {
  return (u32)f2bf(a) | ((u32)f2bf(b) << 16);
}

static __device__ __forceinline__ void async16(void* lds, const void* g) {
  typedef const __attribute__((address_space(1))) unsigned int* gp_t;
  typedef __attribute__((address_space(3))) unsigned int* lp_t;
  __builtin_amdgcn_global_load_lds((gp_t)g, (lp_t)lds, 16, 0, 0);
}

// ---------------- weight transpose + f32->bf16 cast: out[n][k] = in[k][n] ----
__global__ __launch_bounds__(256) void k_transpose(const float* __restrict__ in,
                                                   u16* __restrict__ out,
                                                   int K, int N) {
  __shared__ float t[32][33];
  const int n0 = blockIdx.x * 32, k0 = blockIdx.y * 32;
  const int tx = threadIdx.x & 31, ty = threadIdx.x >> 5;  // 32 x 8
#pragma unroll
  for (int j = 0; j < 4; j++)
    t[ty + j * 8][tx] = in[(size_t)(k0 + ty + j * 8) * N + n0 + tx];
  __syncthreads();
#pragma unroll
  for (int j = 0; j < 4; j++)
    out[(size_t)(n0 + ty + j * 8) * K + k0 + tx] = f2bf(t[tx][ty + j * 8]);
}

// ---------------- layernorm: f32 in -> bf16 out, one wave per row ----------
__global__ __launch_bounds__(256) void k_layernorm(const float* __restrict__ x,
                                                   const float* __restrict__ g,
                                                   const float* __restrict__ b,
                                                   u16* __restrict__ out) {
  const int row  = blockIdx.x * 4 + (threadIdx.x >> 6);
  const int lane = threadIdx.x & 63;
  const float* xr = x + (size_t)row * DM;
  float4 vb[4];
  float s = 0.f, s2 = 0.f;
#pragma unroll
  for (int j = 0; j < 4; j++) {
    float4 v = *(const float4*)(xr + j * 256 + lane * 4);
    vb[j] = v;
    s  += v.x + v.y + v.z + v.w;
    s2 += v.x * v.x + v.y * v.y + v.z * v.z + v.w * v.w;
  }
#pragma unroll
  for (int off = 1; off < 64; off <<= 1) {
    s  += __shfl_xor(s,  off);
    s2 += __shfl_xor(s2, off);
  }
  const float mu   = s * (1.f / DM);
  const float var  = s2 * (1.f / DM) - mu * mu;
  const float rstd = rsqrtf(var + 1e-5f);
  u16* orow = out + (size_t)row * DM;
#pragma unroll
  for (int j = 0; j < 4; j++) {
    const int col = j * 256 + lane * 4;
    uint2 o;
    o.x = pk2bf((vb[j].x - mu) * rstd * g[col + 0] + b[col + 0],
                (vb[j].y - mu) * rstd * g[col + 1] + b[col + 1]);
    o.y = pk2bf((vb[j].z - mu) * rstd * g[col + 2] + b[col + 2],
                (vb[j].w - mu) * rstd * g[col + 3] + b[col + 3]);
    *(uint2*)(orow + col) = o;
  }
}

// ---------------- GEMM: C[M,N] = A[M,K](bf16) @ BT[N,K](bf16)^T + bias -----
// BK=64, XOR-swizzled LDS (slot ^= row&7). EPI: 1 = f32 out (+res),
// 2 = bf16 gelu out, 4 = fused QKV (Q,K row-major; V per-head-transposed)
template <int EPI>
__global__ __launch_bounds__(256) void k_gemm_bt(const u16* __restrict__ A,
                                                 const u16* __restrict__ BT,
                                                 const float* __restrict__ bias0,
                                                 const float* __restrict__ bias1,
                                                 const float* __restrict__ bias2,
                                                 const float* __restrict__ res,
                                                 void* __restrict__ outp,
                                                 int M, int N, int K) {
  __shared__ u16 Al[128 * 64];   // 16 KB
  __shared__ u16 Bl[128 * 64];   // 16 KB
  const int tid = threadIdx.x, wave = tid >> 6, lane = tid & 63;
  // XCD-aware chunked swizzle (nwg % 8 == 0 for all our launches)
  const int nwg = gridDim.x * gridDim.y;
  const int bid = blockIdx.y * gridDim.x + blockIdx.x;
  const int swz = (bid & 7) * (nwg >> 3) + (bid >> 3);
  const int m0 = (swz / gridDim.x) * 128, n0 = (swz % gridDim.x) * 128;
  const int wm = (wave >> 1) * 64, wn = (wave & 1) * 64;
  const int la = lane & 15, lg = lane >> 4;
  fx4 acc[4][4];
#pragma unroll
  for (int i = 0; i < 4; i++)
#pragma unroll
    for (int j = 0; j < 4; j++) acc[i][j] = fx4{0.f, 0.f, 0.f, 0.f};

  // staging: 8 rows x 128B per async16; pre-swizzled global column
  const int srow = lane >> 3;                       // 0..7
  const int sslot = (lane & 7) ^ srow;              // 16B slot, inverse-swizzled
  const u16* ga = A  + (size_t)(m0 + wave * 32 + srow) * K + sslot * 8;
  const u16* gb = BT + (size_t)(n0 + wave * 32 + srow) * K + sslot * 8;
  char* lA = (char*)Al + wave * 4096;
  char* lB = (char*)Bl + wave * 4096;
  const int sw = la & 7;

  for (int k0 = 0; k0 < K; k0 += 64) {
#pragma unroll
    for (int i = 0; i < 4; i++) async16(lA + i * 1024, ga + (size_t)(i * 8) * K + k0);
#pragma unroll
    for (int i = 0; i < 4; i++) async16(lB + i * 1024, gb + (size_t)(i * 8) * K + k0);
    __syncthreads();
#pragma unroll
    for (int kk = 0; kk < 2; kk++) {
      bfx8 av[4], bv[4];
#pragma unroll
      for (int mt = 0; mt < 4; mt++)
        av[mt] = *(const bfx8*)((const char*)Al + (wm + mt * 16 + la) * 128 +
                                (((kk << 2) + lg) ^ sw) * 16);
#pragma unroll
      for (int nt = 0; nt < 4; nt++)
        bv[nt] = *(const bfx8*)((const char*)Bl + (wn + nt * 16 + la) * 128 +
                                (((kk << 2) + lg) ^ sw) * 16);
      __builtin_amdgcn_s_setprio(1);
#pragma unroll
      for (int mt = 0; mt < 4; mt++)
#pragma unroll
        for (int nt = 0; nt < 4; nt++)
          acc[mt][nt] = __builtin_amdgcn_mfma_f32_16x16x32_bf16(av[mt], bv[nt], acc[mt][nt], 0, 0, 0);
      __builtin_amdgcn_s_setprio(0);
    }
    __syncthreads();
  }

  if constexpr (EPI == 4) {
    const int reg = n0 >> 10;  // 0=Q, 1=K, 2=V (block-uniform)
    const float* bp = (reg == 0) ? bias0 : (reg == 1) ? bias1 : bias2;
#pragma unroll
    for (int nt = 0; nt < 4; nt++) {
      const int n  = n0 + wn + nt * 16 + la;
      const int nl = n & 1023;
      const float bs = bp[nl];
      if (reg < 2) {
        u16* base = (u16*)outp + (size_t)reg * (8u * 1024 * 1024);
#pragma unroll
        for (int mt = 0; mt < 4; mt++)
#pragma unroll
          for (int vv = 0; vv < 4; vv++) {
            const int m = m0 + wm + mt * 16 + lg * 4 + vv;
            base[(size_t)m * 1024 + nl] = f2bf(acc[mt][nt][vv] + bs);
          }
      } else {
        const int hh = nl >> 6, d = nl & 63;
#pragma unroll
        for (int mt = 0; mt < 4; mt++) {
          const int m = m0 + wm + mt * 16 + lg * 4;
          const int bb = m >> 11, s = m & 2047;
          u16* vp = (u16*)outp + 16u * 1024 * 1024 +
                    (((size_t)bb * NH + hh) * DK + d) * SS + s;
          uint2 o;
          o.x = pk2bf(acc[mt][nt][0] + bs, acc[mt][nt][1] + bs);
          o.y = pk2bf(acc[mt][nt][2] + bs, acc[mt][nt][3] + bs);
          *(uint2*)vp = o;
        }
      }
    }
  } else {
#pragma unroll
    for (int nt = 0; nt < 4; nt++) {
      const int n = n0 + wn + nt * 16 + la;
      const float bs = bias0[n];
#pragma unroll
      for (int mt = 0; mt < 4; mt++) {
#pragma unroll
        for (int vv = 0; vv < 4; vv++) {
          const int m = m0 + wm + mt * 16 + lg * 4 + vv;
          const float val = acc[mt][nt][vv] + bs;
          const size_t idx = (size_t)m * N + n;
          if constexpr (EPI == 1) {
            ((float*)outp)[idx] = res[idx] + val;
          } else {
            const float gl = 0.5f * val * (1.f + erff(val * 0.70710678118f));
            ((u16*)outp)[idx] = f2bf(gl);
          }
        }
      }
    }
  }
}

// ---------------- causal flash attention, swapped-QK^T, split-KV ----------
// grid 1024 x 512 threads = 8 waves = 2 groups of 4. Per block: 128 q-rows.
// Group g processes KV chunks (2i+g)*64; each group has its own double-buffered
// K/V in LDS (64 KB total). End: merge the two online-softmax partials via LDS.
// Softmax is shuffle-free on the deferred (common) path; lsum cross-lane
// reduced once in the epilogue. bid->(bq,b,h): heavy blocks dispatch first,
// all q-blocks of one (b,h) share bid%8 -> same XCD L2.
__global__ __launch_bounds__(512, 4) void k_attn(const u16* __restrict__ q,
                                                 const u16* __restrict__ k,
                                                 const u16* __restrict__ vt,
                                                 u16* __restrict__ att) {
  __shared__ char sm[65536];   // [group][ K 2x8KB | V 2x8KB ]; merge scratch aliases
  const int bid = blockIdx.x;
  const int bq = 15 - (bid >> 6);
  const int bh = bid & 63;
  const int b = bh >> 4, h = bh & 15;

  const int tid = threadIdx.x, wave = tid >> 6, lane = tid & 63;
  const int g = wave >> 2, wv4 = wave & 3;
  const int la = lane & 15, lg = lane >> 4;
  const int q0 = bq * 128;

  // Q fragments (B-operand): lane holds Q[q=qt*16+la][d = f*32 + lg*8 + j]
  bfx8 qf[2][2];
#pragma unroll
  for (int qt = 0; qt < 2; qt++) {
    const u16* qp = q + (size_t)(b * SS + q0 + wv4 * 32 + qt * 16 + la) * DM + h * DK + lg * 8;
#pragma unroll
    for (int f = 0; f < 2; f++) qf[qt][f] = *(const bfx8*)(qp + f * 32);
  }

  fx4 acc[2][4];
#pragma unroll
  for (int qt = 0; qt < 2; qt++)
#pragma unroll
    for (int dt = 0; dt < 4; dt++) acc[qt][dt] = fx4{0.f, 0.f, 0.f, 0.f};
  float mold[2] = {-10000.f, -10000.f};   // finite floor (log2 units)
  float lsum[2] = {0.f, 0.f};             // per-lane partial

  // staging (pre-swizzled global source, linear LDS dest)
  const int srow = lane >> 3;                   // 0..7
  const int sslot = (lane & 7) ^ srow;          // 16B slot
  const u16* kg0 = k  + (size_t)(b * SS + wv4 * 16 + srow) * DM + h * DK + sslot * 8;
  const u16* vg0 = vt + (size_t)((b * NH + h) * DK + wv4 * 16 + srow) * SS + sslot * 8;
  char* kbase = sm + g * 32768 + wv4 * 2048;            // + buf*8192
  char* vbase = sm + g * 32768 + 16384 + wv4 * 2048;

  const float c1 = 0.18033688f;  // 0.125 * log2(e)
  const int niter = bq + 1;      // chunks for this group: c = 2*i + g

  auto stage = [&](int buf, int i) {
    const int c0 = (2 * i + g) * 64;
#pragma unroll
    for (int j = 0; j < 2; j++)
      async16(kbase + buf * 8192 + j * 1024, kg0 + (size_t)(c0 + j * 8) * DM);
#pragma unroll
    for (int j = 0; j < 2; j++)
      async16(vbase + buf * 8192 + j * 1024, vg0 + (size_t)(j * 8) * SS + c0);
  };

  stage(0, 0);
  int cur = 0;
  const int sw = la & 7;

  for (int i = 0; i < niter; i++) {
    __syncthreads();                 // buf[cur] staged; prev reads done
    if (i + 1 < niter) stage(cur ^ 1, i + 1);
    const int c0 = (2 * i + g) * 64;
    const bool msk = (i == niter - 1);
    const char* Kb = sm + g * 32768 + cur * 8192;
    const char* Vb = sm + g * 32768 + 16384 + cur * 8192;

    // ---- S^T = K @ Q^T : lane holds S^T[kv=t*16+lg*4+r][q=qt*16+la] ----
    fx4 st[2][4];
    __builtin_amdgcn_s_setprio(1);
#pragma unroll
    for (int t = 0; t < 4; t++) {
      const char* kr = Kb + (size_t)(t * 16 + la) * 128;
      bfx8 kf0 = *(const bfx8*)(kr + ((0 + lg) ^ sw) * 16);
      bfx8 kf1 = *(const bfx8*)(kr + ((4 + lg) ^ sw) * 16);
#pragma unroll
      for (int qt = 0; qt < 2; qt++) {
        fx4 z = fx4{0.f, 0.f, 0.f, 0.f};
        z = __builtin_amdgcn_mfma_f32_16x16x32_bf16(kf0, qf[qt][0], z, 0, 0, 0);
        z = __builtin_amdgcn_mfma_f32_16x16x32_bf16(kf1, qf[qt][1], z, 0, 0, 0);
        st[qt][t] = z;
      }
    }
    __builtin_amdgcn_s_setprio(0);

    if (msk) {
#pragma unroll
      for (int qt = 0; qt < 2; qt++) {
        const int qir = q0 + wv4 * 32 + qt * 16 + la;
#pragma unroll
        for (int t = 0; t < 4; t++)
#pragma unroll
          for (int r = 0; r < 4; r++)
            if (c0 + t * 16 + lg * 4 + r > qir) st[qt][t][r] = -1e9f;
      }
    }

    // ---- softmax: shuffle-free deferred path; per-lane partial lsum ----
    float lmx[2];
#pragma unroll
    for (int qt = 0; qt < 2; qt++) {
      float mx = fmaxf(fmaxf(st[qt][0][0], st[qt][0][1]), fmaxf(st[qt][0][2], st[qt][0][3]));
#pragma unroll
      for (int t = 1; t < 4; t++)
        mx = fmaxf(mx, fmaxf(fmaxf(st[qt][t][0], st[qt][t][1]), fmaxf(st[qt][t][2], st[qt][t][3])));
      lmx[qt] = mx * c1;
    }
    const bool def = (lmx[0] <= mold[0] + 8.f) && (lmx[1] <= mold[1] + 8.f);
    if (!__all(def)) {
#pragma unroll
      for (int qt = 0; qt < 2; qt++) {
        float mx = lmx[qt];
        mx = fmaxf(mx, __shfl_xor(mx, 16));
        mx = fmaxf(mx, __shfl_xor(mx, 32));
        const float mnew  = fmaxf(mold[qt], mx);
        const float scale = exp2f(mold[qt] - mnew);
        mold[qt] = mnew;
        lsum[qt] *= scale;
#pragma unroll
        for (int dt = 0; dt < 4; dt++) {
          acc[qt][dt][0] *= scale; acc[qt][dt][1] *= scale;
          acc[qt][dt][2] *= scale; acc[qt][dt][3] *= scale;
        }
      }
    }
    u32 W[2][4][2];
#pragma unroll
    for (int qt = 0; qt < 2; qt++) {
      float ps = 0.f;
#pragma unroll
      for (int t = 0; t < 4; t++) {
        float p0 = exp2f(fmaf(st[qt][t][0], c1, -mold[qt]));
        float p1 = exp2f(fmaf(st[qt][t][1], c1, -mold[qt]));
        float p2 = exp2f(fmaf(st[qt][t][2], c1, -mold[qt]));
        float p3 = exp2f(fmaf(st[qt][t][3], c1, -mold[qt]));
        ps += (p0 + p1) + (p2 + p3);
        W[qt][t][0] = pk2bf(p0, p1);
        W[qt][t][1] = pk2bf(p2, p3);
      }
      lsum[qt] += ps;
    }

    // ---- PV: O^T += V^T @ P^T (P B-frag rebuilt in-register via shfl) ----
    const int sLo = la + ((lg & 1) << 5);
    const int sHi = sLo + 16;
    const bool tHi = (lg >> 1) & 1;
#pragma unroll
    for (int f = 0; f < 2; f++) {
      bfx8 pf[2];
#pragma unroll
      for (int qt = 0; qt < 2; qt++) {
        const u32 a0 = __shfl(W[qt][2 * f][0], sLo), b0 = __shfl(W[qt][2 * f + 1][0], sLo);
        const u32 a1 = __shfl(W[qt][2 * f][1], sLo), b1 = __shfl(W[qt][2 * f + 1][1], sLo);
        const u32 a2 = __shfl(W[qt][2 * f][0], sHi), b2 = __shfl(W[qt][2 * f + 1][0], sHi);
        const u32 a3 = __shfl(W[qt][2 * f][1], sHi), b3 = __shfl(W[qt][2 * f + 1][1], sHi);
        union { u32 u[4]; bfx8 v; } pu;
        pu.u[0] = tHi ? b0 : a0;
        pu.u[1] = tHi ? b1 : a1;
        pu.u[2] = tHi ? b2 : a2;
        pu.u[3] = tHi ? b3 : a3;
        pf[qt] = pu.v;
      }
      __builtin_amdgcn_s_setprio(1);
#pragma unroll
      for (int dt = 0; dt < 4; dt++) {
        const int row = dt * 16 + la;
        bfx8 vf = *(const bfx8*)(Vb + (size_t)row * 128 + (((f << 2) + lg) ^ sw) * 16);
        acc[0][dt] = __builtin_amdgcn_mfma_f32_16x16x32_bf16(vf, pf[0], acc[0][dt], 0, 0, 0);
        acc[1][dt] = __builtin_amdgcn_mfma_f32_16x16x32_bf16(vf, pf[1], acc[1][dt], 0, 0, 0);
      }
      __builtin_amdgcn_s_setprio(0);
    }
    cur ^= 1;
  }

  // ---- finalize per-group lsum (cross-lane, once) ----
#pragma unroll
  for (int qt = 0; qt < 2; qt++) {
    lsum[qt] += __shfl_xor(lsum[qt], 16);
    lsum[qt] += __shfl_xor(lsum[qt], 32);
  }

  // ---- merge group partials via LDS scratch (KV buffers dead) ----
  __syncthreads();
  const int gi = wv4 * 64 + lane;                  // 0..255 within group
  float* scr = (float*)sm + (size_t)gi * 36;       // 36 KB
  if (g == 1) {
#pragma unroll
    for (int qt = 0; qt < 2; qt++)
#pragma unroll
      for (int dt = 0; dt < 4; dt++)
#pragma unroll
        for (int j = 0; j < 4; j++) scr[qt * 16 + dt * 4 + j] = acc[qt][dt][j];
    scr[32] = mold[0]; scr[33] = mold[1];
    scr[34] = lsum[0]; scr[35] = lsum[1];
  }
  __syncthreads();
  if (g == 0) {
#pragma unroll
    for (int qt = 0; qt < 2; qt++) {
      const float mB = scr[32 + qt], lB = scr[34 + qt];
      const float mN = fmaxf(mold[qt], mB);
      const float sA = exp2f(mold[qt] - mN);
      const float sB = exp2f(mB - mN);
      const float inv = 1.f / (lsum[qt] * sA + lB * sB);
      u16* ob = att + (size_t)(b * SS + q0 + wv4 * 32 + qt * 16 + la) * DM + h * DK + lg * 4;
#pragma unroll
      for (int dt = 0; dt < 4; dt++) {
        float o0 = (acc[qt][dt][0] * sA + scr[qt * 16 + dt * 4 + 0] * sB) * inv;
        float o1 = (acc[qt][dt][1] * sA + scr[qt * 16 + dt * 4 + 1] * sB) * inv;
        float o2 = (acc[qt][dt][2] * sA + scr[qt * 16 + dt * 4 + 2] * sB) * inv;
        float o3 = (acc[qt][dt][3] * sA + scr[qt * 16 + dt * 4 + 3] * sB) * inv;
        uint2 o;
        o.x = pk2bf(o0, o1);
        o.y = pk2bf(o2, o3);
        *(uint2*)(ob + dt * 16) = o;
      }
    }
  }
}

// ---------------------------------------------------------------------------
extern "C" void kernel_launch(void* const* d_in, const int* in_sizes, int n_in,
                              void* d_out, int out_size, void* d_ws, size_t ws_size,
                              hipStream_t stream) {
  const float* x    = (const float*)d_in[0];
  const float* wq   = (const float*)d_in[1];
  const float* bq   = (const float*)d_in[2];
  const float* wk   = (const float*)d_in[3];
  const float* bk   = (const float*)d_in[4];
  const float* wv   = (const float*)d_in[5];
  const float* bv   = (const float*)d_in[6];
  const float* wo   = (const float*)d_in[7];
  const float* bo   = (const float*)d_in[8];
  const float* w1   = (const float*)d_in[9];
  const float* b1   = (const float*)d_in[10];
  const float* w2   = (const float*)d_in[11];
  const float* b2   = (const float*)d_in[12];
  const float* ln1g = (const float*)d_in[13];
  const float* ln1b = (const float*)d_in[14];
  const float* ln2g = (const float*)d_in[15];
  const float* ln2b = (const float*)d_in[16];
  float* out = (float*)d_out;

  char* w = (char*)d_ws;
  const size_t MB = 1024ull * 1024ull;
  u16*   wqkv = (u16*)(w + 0 * MB);   // [3072][1024] bf16 (Q,K,V stacked)
  u16*   wot  = (u16*)(w + 6 * MB);   // [1024][1024]
  u16*   w1t  = (u16*)(w + 8 * MB);   // [4096][1024]
  u16*   w2t  = (u16*)(w + 16 * MB);  // [1024][4096]
  float* x2   = (float*)(w + 24 * MB);// [8192][1024] f32
  u16*   hb   = (u16*)(w + 56 * MB);  // [8192][1024] (h, then h2)
  u16*   qb   = (u16*)(w + 72 * MB);  // [8192][1024]; K at +8M u16, V^T at +16M u16
  u16*   kb   = (u16*)(w + 88 * MB);
  u16*   vtb  = (u16*)(w + 104 * MB); // [4][16][64][2048] V^T per head
  u16*   atb  = (u16*)(w + 120 * MB); // [8192][1024]
  u16*   ffb  = (u16*)(w + 72 * MB);  // [8192][4096] overlays q/k/vt/att

  // 1) weight transposes (f32 -> bf16 W^T); QKV stacked into one [3072][1024]
  k_transpose<<<dim3(32, 32),  256, 0, stream>>>(wq, wqkv,               1024, 1024);
  k_transpose<<<dim3(32, 32),  256, 0, stream>>>(wk, wqkv + 1024 * 1024, 1024, 1024);
  k_transpose<<<dim3(32, 32),  256, 0, stream>>>(wv, wqkv + 2048 * 1024, 1024, 1024);
  k_transpose<<<dim3(32, 32),  256, 0, stream>>>(wo, wot, 1024, 1024);
  k_transpose<<<dim3(128, 32), 256, 0, stream>>>(w1, w1t, 1024, 4096);
  k_transpose<<<dim3(32, 128), 256, 0, stream>>>(w2, w2t, 4096, 1024);

  // 2) LN1: x -> h (bf16)
  k_layernorm<<<MROWS / 4, 256, 0, stream>>>(x, ln1g, ln1b, hb);

  // 3) fused QKV projection (Q,K row-major bf16; V per-head-transposed)
  k_gemm_bt<4><<<dim3(24, 64), 256, 0, stream>>>(hb, wqkv, bq, bk, bv, nullptr, qb,
                                                 MROWS, 3 * DM, DM);

  // 4) causal flash attention (swapped QK^T, split-KV, 8 waves)
  k_attn<<<dim3(1024), 512, 0, stream>>>(qb, kb, vtb, atb);

  // 5) O projection + residual (f32 x2)
  k_gemm_bt<1><<<dim3(8, 64), 256, 0, stream>>>(atb, wot, bo, nullptr, nullptr, x, x2,
                                                MROWS, DM, DM);

  // 6) LN2: x2 -> h2 (bf16, reuse hb)
  k_layernorm<<<MROWS / 4, 256, 0, stream>>>(x2, ln2g, ln2b, hb);

  // 7) FF1 + GELU
  k_gemm_bt<2><<<dim3(32, 64), 256, 0, stream>>>(hb, w1t, b1, nullptr, nullptr, nullptr, ffb,
                                                 MROWS, DFF, DM);

  // 8) FF2 + residual -> d_out (f32)
  k_gemm_bt<1><<<dim3(8, 64), 256, 0, stream>>>(ffb, w2t, b2, nullptr, nullptr, x2, out,
                                                MROWS, DM, DFF);
}

// Round 6
// 398.078 us; speedup vs baseline: 1.9984x; 1.0193x over previous
//
#include <hip/hip_runtime.h>
#include <hip/hip_bf16.h>

#define DM   1024
#define DFF  4096
#define NB   4
#define SS   2048
#define NH   16
#define DK   64
#define MROWS (NB*SS)   // 8192

typedef __attribute__((ext_vector_type(8))) short bfx8;
typedef __attribute__((ext_vector_type(4))) float fx4;
typedef unsigned int u32;
typedef unsigned short u16;

static __device__ __forceinline__ u16 f2bf(float f) {
  union { __hip_bfloat16 h; u16 u; } cv;
  cv.h = __float2bfloat16(f);
  return cv.u;
}
static __device__ __forceinline__ u32 pk2bf(float a, float b) {
  return (u32)f2bf(a) | ((u32)f2bf(b) << 16);
}

static __device__ __forceinline__ void async16(void* lds, const void* g) {
  typedef const __attribute__((address_space(1))) unsigned int* gp_t;
  typedef __attribute__((address_space(3))) unsigned int* lp_t;
  __builtin_amdgcn_global_load_lds((gp_t)g, (lp_t)lds, 16, 0, 0);
}

// ---------------- weight transpose + f32->bf16 cast: out[n][k] = in[k][n] ----
__global__ __launch_bounds__(256) void k_transpose(const float* __restrict__ in,
                                                   u16* __restrict__ out,
                                                   int K, int N) {
  __shared__ float t[32][33];
  const int n0 = blockIdx.x * 32, k0 = blockIdx.y * 32;
  const int tx = threadIdx.x & 31, ty = threadIdx.x >> 5;  // 32 x 8
#pragma unroll
  for (int j = 0; j < 4; j++)
    t[ty + j * 8][tx] = in[(size_t)(k0 + ty + j * 8) * N + n0 + tx];
  __syncthreads();
#pragma unroll
  for (int j = 0; j < 4; j++)
    out[(size_t)(n0 + ty + j * 8) * K + k0 + tx] = f2bf(t[tx][ty + j * 8]);
}

// ---------------- layernorm: f32 in -> bf16 out, one wave per row ----------
__global__ __launch_bounds__(256) void k_layernorm(const float* __restrict__ x,
                                                   const float* __restrict__ g,
                                                   const float* __restrict__ b,
                                                   u16* __restrict__ out) {
  const int row  = blockIdx.x * 4 + (threadIdx.x >> 6);
  const int lane = threadIdx.x & 63;
  const float* xr = x + (size_t)row * DM;
  float4 vb[4];
  float s = 0.f, s2 = 0.f;
#pragma unroll
  for (int j = 0; j < 4; j++) {
    float4 v = *(const float4*)(xr + j * 256 + lane * 4);
    vb[j] = v;
    s  += v.x + v.y + v.z + v.w;
    s2 += v.x * v.x + v.y * v.y + v.z * v.z + v.w * v.w;
  }
#pragma unroll
  for (int off = 1; off < 64; off <<= 1) {
    s  += __shfl_xor(s,  off);
    s2 += __shfl_xor(s2, off);
  }
  const float mu   = s * (1.f / DM);
  const float var  = s2 * (1.f / DM) - mu * mu;
  const float rstd = rsqrtf(var + 1e-5f);
  u16* orow = out + (size_t)row * DM;
#pragma unroll
  for (int j = 0; j < 4; j++) {
    const int col = j * 256 + lane * 4;
    uint2 o;
    o.x = pk2bf((vb[j].x - mu) * rstd * g[col + 0] + b[col + 0],
                (vb[j].y - mu) * rstd * g[col + 1] + b[col + 1]);
    o.y = pk2bf((vb[j].z - mu) * rstd * g[col + 2] + b[col + 2],
                (vb[j].w - mu) * rstd * g[col + 3] + b[col + 3]);
    *(uint2*)(orow + col) = o;
  }
}

// ---------------- GEMM: C[M,N] = A[M,K](bf16) @ BT[N,K](bf16)^T + bias -----
// BK=64, double-buffered LDS, counted-vmcnt pipeline (no vmcnt(0) drain in
// main loop), XOR-swizzled LDS (slot ^= row&7). EPI: 1 = f32 out (+res),
// 2 = bf16 gelu out, 4 = fused QKV (Q,K row-major; V per-head-transposed)
template <int EPI>
__global__ __launch_bounds__(256) void k_gemm_bt(const u16* __restrict__ A,
                                                 const u16* __restrict__ BT,
                                                 const float* __restrict__ bias0,
                                                 const float* __restrict__ bias1,
                                                 const float* __restrict__ bias2,
                                                 const float* __restrict__ res,
                                                 void* __restrict__ outp,
                                                 int M, int N, int K) {
  __shared__ u16 Al[2 * 128 * 64];   // 32 KB (two 16 KB buffers)
  __shared__ u16 Bl[2 * 128 * 64];   // 32 KB
  const int tid = threadIdx.x, wave = tid >> 6, lane = tid & 63;
  // XCD-aware chunked swizzle (nwg % 8 == 0 for all our launches)
  const int nwg = gridDim.x * gridDim.y;
  const int bid = blockIdx.y * gridDim.x + blockIdx.x;
  const int swz = (bid & 7) * (nwg >> 3) + (bid >> 3);
  const int m0 = (swz / gridDim.x) * 128, n0 = (swz % gridDim.x) * 128;
  const int wm = (wave >> 1) * 64, wn = (wave & 1) * 64;
  const int la = lane & 15, lg = lane >> 4;
  fx4 acc[4][4];
#pragma unroll
  for (int i = 0; i < 4; i++)
#pragma unroll
    for (int j = 0; j < 4; j++) acc[i][j] = fx4{0.f, 0.f, 0.f, 0.f};

  // staging: 8 rows x 128B per async16; pre-swizzled global column
  const int srow = lane >> 3;                       // 0..7
  const int sslot = (lane & 7) ^ srow;              // 16B slot, inverse-swizzled
  const u16* ga = A  + (size_t)(m0 + wave * 32 + srow) * K + sslot * 8;
  const u16* gb = BT + (size_t)(n0 + wave * 32 + srow) * K + sslot * 8;
  char* lA = (char*)Al + wave * 4096;               // wave quarter in buffer 0
  char* lB = (char*)Bl + wave * 4096;
  const int sw = la & 7;

  auto stageg = [&](int buf, int k0) {
#pragma unroll
    for (int i = 0; i < 4; i++)
      async16(lA + buf * 16384 + i * 1024, ga + (size_t)(i * 8) * K + k0);
#pragma unroll
    for (int i = 0; i < 4; i++)
      async16(lB + buf * 16384 + i * 1024, gb + (size_t)(i * 8) * K + k0);
  };

  const int nk = K >> 6;
  stageg(0, 0);
  stageg(1, 64);
  int cur = 0;

  for (int t = 0; t < nk; ++t) {
    // wait ONLY for the oldest tile's 8 loads; next tile's stay in flight
    if (t < nk - 1) { asm volatile("s_waitcnt vmcnt(8)" ::: "memory"); }
    else            { asm volatile("s_waitcnt vmcnt(0)" ::: "memory"); }
    __builtin_amdgcn_s_barrier();
    asm volatile("" ::: "memory");
    const char* Ab = (const char*)Al + cur * 16384;
    const char* Bb = (const char*)Bl + cur * 16384;
#pragma unroll
    for (int kk = 0; kk < 2; kk++) {
      bfx8 av[4], bv[4];
#pragma unroll
      for (int mt = 0; mt < 4; mt++)
        av[mt] = *(const bfx8*)(Ab + (wm + mt * 16 + la) * 128 +
                                (((kk << 2) + lg) ^ sw) * 16);
#pragma unroll
      for (int nt = 0; nt < 4; nt++)
        bv[nt] = *(const bfx8*)(Bb + (wn + nt * 16 + la) * 128 +
                                (((kk << 2) + lg) ^ sw) * 16);
      __builtin_amdgcn_s_setprio(1);
#pragma unroll
      for (int mt = 0; mt < 4; mt++)
#pragma unroll
        for (int nt = 0; nt < 4; nt++)
          acc[mt][nt] = __builtin_amdgcn_mfma_f32_16x16x32_bf16(av[mt], bv[nt], acc[mt][nt], 0, 0, 0);
      __builtin_amdgcn_s_setprio(0);
    }
    asm volatile("" ::: "memory");
    __builtin_amdgcn_s_barrier();      // all waves done reading buf[cur]
    if (t + 2 < nk) stageg(cur, (t + 2) << 6);
    cur ^= 1;
  }

  if constexpr (EPI == 4) {
    const int reg = n0 >> 10;  // 0=Q, 1=K, 2=V (block-uniform)
    const float* bp = (reg == 0) ? bias0 : (reg == 1) ? bias1 : bias2;
#pragma unroll
    for (int nt = 0; nt < 4; nt++) {
      const int n  = n0 + wn + nt * 16 + la;
      const int nl = n & 1023;
      const float bs = bp[nl];
      if (reg < 2) {
        u16* base = (u16*)outp + (size_t)reg * (8u * 1024 * 1024);
#pragma unroll
        for (int mt = 0; mt < 4; mt++)
#pragma unroll
          for (int vv = 0; vv < 4; vv++) {
            const int m = m0 + wm + mt * 16 + lg * 4 + vv;
            base[(size_t)m * 1024 + nl] = f2bf(acc[mt][nt][vv] + bs);
          }
      } else {
        const int hh = nl >> 6, d = nl & 63;
#pragma unroll
        for (int mt = 0; mt < 4; mt++) {
          const int m = m0 + wm + mt * 16 + lg * 4;
          const int bb = m >> 11, s = m & 2047;
          u16* vp = (u16*)outp + 16u * 1024 * 1024 +
                    (((size_t)bb * NH + hh) * DK + d) * SS + s;
          uint2 o;
          o.x = pk2bf(acc[mt][nt][0] + bs, acc[mt][nt][1] + bs);
          o.y = pk2bf(acc[mt][nt][2] + bs, acc[mt][nt][3] + bs);
          *(uint2*)vp = o;
        }
      }
    }
  } else {
#pragma unroll
    for (int nt = 0; nt < 4; nt++) {
      const int n = n0 + wn + nt * 16 + la;
      const float bs = bias0[n];
#pragma unroll
      for (int mt = 0; mt < 4; mt++) {
#pragma unroll
        for (int vv = 0; vv < 4; vv++) {
          const int m = m0 + wm + mt * 16 + lg * 4 + vv;
          const float val = acc[mt][nt][vv] + bs;
          const size_t idx = (size_t)m * N + n;
          if constexpr (EPI == 1) {
            ((float*)outp)[idx] = res[idx] + val;
          } else {
            const float gl = 0.5f * val * (1.f + erff(val * 0.70710678118f));
            ((u16*)outp)[idx] = f2bf(gl);
          }
        }
      }
    }
  }
}

// ---------------- causal flash attention, swapped-QK^T, split-KV ----------
// grid 1024 x 512 threads = 8 waves = 2 groups of 4. Per block: 128 q-rows.
// Group g processes KV chunks (2i+g)*64; each group has its own double-buffered
// K/V in LDS (64 KB total). End: merge the two online-softmax partials via LDS.
__global__ __launch_bounds__(512, 4) void k_attn(const u16* __restrict__ q,
                                                 const u16* __restrict__ k,
                                                 const u16* __restrict__ vt,
                                                 u16* __restrict__ att) {
  __shared__ char sm[65536];   // [group][ K 2x8KB | V 2x8KB ]; merge scratch aliases
  const int bid = blockIdx.x;
  const int bq = 15 - (bid >> 6);
  const int bh = bid & 63;
  const int b = bh >> 4, h = bh & 15;

  const int tid = threadIdx.x, wave = tid >> 6, lane = tid & 63;
  const int g = wave >> 2, wv4 = wave & 3;
  const int la = lane & 15, lg = lane >> 4;
  const int q0 = bq * 128;

  // Q fragments (B-operand): lane holds Q[q=qt*16+la][d = f*32 + lg*8 + j]
  bfx8 qf[2][2];
#pragma unroll
  for (int qt = 0; qt < 2; qt++) {
    const u16* qp = q + (size_t)(b * SS + q0 + wv4 * 32 + qt * 16 + la) * DM + h * DK + lg * 8;
#pragma unroll
    for (int f = 0; f < 2; f++) qf[qt][f] = *(const bfx8*)(qp + f * 32);
  }

  fx4 acc[2][4];
#pragma unroll
  for (int qt = 0; qt < 2; qt++)
#pragma unroll
    for (int dt = 0; dt < 4; dt++) acc[qt][dt] = fx4{0.f, 0.f, 0.f, 0.f};
  float mold[2] = {-10000.f, -10000.f};   // finite floor (log2 units)
  float lsum[2] = {0.f, 0.f};             // per-lane partial

  // staging (pre-swizzled global source, linear LDS dest)
  const int srow = lane >> 3;                   // 0..7
  const int sslot = (lane & 7) ^ srow;          // 16B slot
  const u16* kg0 = k  + (size_t)(b * SS + wv4 * 16 + srow) * DM + h * DK + sslot * 8;
  const u16* vg0 = vt + (size_t)((b * NH + h) * DK + wv4 * 16 + srow) * SS + sslot * 8;
  char* kbase = sm + g * 32768 + wv4 * 2048;            // + buf*8192
  char* vbase = sm + g * 32768 + 16384 + wv4 * 2048;

  const float c1 = 0.18033688f;  // 0.125 * log2(e)
  const int niter = bq + 1;      // chunks for this group: c = 2*i + g

  auto stage = [&](int buf, int i) {
    const int c0 = (2 * i + g) * 64;
#pragma unroll
    for (int j = 0; j < 2; j++)
      async16(kbase + buf * 8192 + j * 1024, kg0 + (size_t)(c0 + j * 8) * DM);
#pragma unroll
    for (int j = 0; j < 2; j++)
      async16(vbase + buf * 8192 + j * 1024, vg0 + (size_t)(j * 8) * SS + c0);
  };

  stage(0, 0);
  int cur = 0;
  const int sw = la & 7;

  for (int i = 0; i < niter; i++) {
    __syncthreads();                 // buf[cur] staged; prev reads done
    if (i + 1 < niter) stage(cur ^ 1, i + 1);
    const int c0 = (2 * i + g) * 64;
    const bool msk = (i == niter - 1);
    const char* Kb = sm + g * 32768 + cur * 8192;
    const char* Vb = sm + g * 32768 + 16384 + cur * 8192;

    // ---- S^T = K @ Q^T : lane holds S^T[kv=t*16+lg*4+r][q=qt*16+la] ----
    fx4 st[2][4];
    __builtin_amdgcn_s_setprio(1);
#pragma unroll
    for (int t = 0; t < 4; t++) {
      const char* kr = Kb + (size_t)(t * 16 + la) * 128;
      bfx8 kf0 = *(const bfx8*)(kr + ((0 + lg) ^ sw) * 16);
      bfx8 kf1 = *(const bfx8*)(kr + ((4 + lg) ^ sw) * 16);
#pragma unroll
      for (int qt = 0; qt < 2; qt++) {
        fx4 z = fx4{0.f, 0.f, 0.f, 0.f};
        z = __builtin_amdgcn_mfma_f32_16x16x32_bf16(kf0, qf[qt][0], z, 0, 0, 0);
        z = __builtin_amdgcn_mfma_f32_16x16x32_bf16(kf1, qf[qt][1], z, 0, 0, 0);
        st[qt][t] = z;
      }
    }
    __builtin_amdgcn_s_setprio(0);

    if (msk) {
#pragma unroll
      for (int qt = 0; qt < 2; qt++) {
        const int qir = q0 + wv4 * 32 + qt * 16 + la;
#pragma unroll
        for (int t = 0; t < 4; t++)
#pragma unroll
          for (int r = 0; r < 4; r++)
            if (c0 + t * 16 + lg * 4 + r > qir) st[qt][t][r] = -1e9f;
      }
    }

    // ---- softmax: shuffle-free deferred path; per-lane partial lsum ----
    float lmx[2];
#pragma unroll
    for (int qt = 0; qt < 2; qt++) {
      float mx = fmaxf(fmaxf(st[qt][0][0], st[qt][0][1]), fmaxf(st[qt][0][2], st[qt][0][3]));
#pragma unroll
      for (int t = 1; t < 4; t++)
        mx = fmaxf(mx, fmaxf(fmaxf(st[qt][t][0], st[qt][t][1]), fmaxf(st[qt][t][2], st[qt][t][3])));
      lmx[qt] = mx * c1;
    }
    const bool def = (lmx[0] <= mold[0] + 8.f) && (lmx[1] <= mold[1] + 8.f);
    if (!__all(def)) {
#pragma unroll
      for (int qt = 0; qt < 2; qt++) {
        float mx = lmx[qt];
        mx = fmaxf(mx, __shfl_xor(mx, 16));
        mx = fmaxf(mx, __shfl_xor(mx, 32));
        const float mnew  = fmaxf(mold[qt], mx);
        const float scale = exp2f(mold[qt] - mnew);
        mold[qt] = mnew;
        lsum[qt] *= scale;
#pragma unroll
        for (int dt = 0; dt < 4; dt++) {
          acc[qt][dt][0] *= scale; acc[qt][dt][1] *= scale;
          acc[qt][dt][2] *= scale; acc[qt][dt][3] *= scale;
        }
      }
    }
    u32 W[2][4][2];
#pragma unroll
    for (int qt = 0; qt < 2; qt++) {
      float ps = 0.f;
#pragma unroll
      for (int t = 0; t < 4; t++) {
        float p0 = exp2f(fmaf(st[qt][t][0], c1, -mold[qt]));
        float p1 = exp2f(fmaf(st[qt][t][1], c1, -mold[qt]));
        float p2 = exp2f(fmaf(st[qt][t][2], c1, -mold[qt]));
        float p3 = exp2f(fmaf(st[qt][t][3], c1, -mold[qt]));
        ps += (p0 + p1) + (p2 + p3);
        W[qt][t][0] = pk2bf(p0, p1);
        W[qt][t][1] = pk2bf(p2, p3);
      }
      lsum[qt] += ps;
    }

    // ---- PV: O^T += V^T @ P^T (P B-frag rebuilt in-register via shfl) ----
    const int sLo = la + ((lg & 1) << 5);
    const int sHi = sLo + 16;
    const bool tHi = (lg >> 1) & 1;
#pragma unroll
    for (int f = 0; f < 2; f++) {
      bfx8 pf[2];
#pragma unroll
      for (int qt = 0; qt < 2; qt++) {
        const u32 a0 = __shfl(W[qt][2 * f][0], sLo), b0 = __shfl(W[qt][2 * f + 1][0], sLo);
        const u32 a1 = __shfl(W[qt][2 * f][1], sLo), b1 = __shfl(W[qt][2 * f + 1][1], sLo);
        const u32 a2 = __shfl(W[qt][2 * f][0], sHi), b2 = __shfl(W[qt][2 * f + 1][0], sHi);
        const u32 a3 = __shfl(W[qt][2 * f][1], sHi), b3 = __shfl(W[qt][2 * f + 1][1], sHi);
        union { u32 u[4]; bfx8 v; } pu;
        pu.u[0] = tHi ? b0 : a0;
        pu.u[1] = tHi ? b1 : a1;
        pu.u[2] = tHi ? b2 : a2;
        pu.u[3] = tHi ? b3 : a3;
        pf[qt] = pu.v;
      }
      __builtin_amdgcn_s_setprio(1);
#pragma unroll
      for (int dt = 0; dt < 4; dt++) {
        const int row = dt * 16 + la;
        bfx8 vf = *(const bfx8*)(Vb + (size_t)row * 128 + (((f << 2) + lg) ^ sw) * 16);
        acc[0][dt] = __builtin_amdgcn_mfma_f32_16x16x32_bf16(vf, pf[0], acc[0][dt], 0, 0, 0);
        acc[1][dt] = __builtin_amdgcn_mfma_f32_16x16x32_bf16(vf, pf[1], acc[1][dt], 0, 0, 0);
      }
      __builtin_amdgcn_s_setprio(0);
    }
    cur ^= 1;
  }

  // ---- finalize per-group lsum (cross-lane, once) ----
#pragma unroll
  for (int qt = 0; qt < 2; qt++) {
    lsum[qt] += __shfl_xor(lsum[qt], 16);
    lsum[qt] += __shfl_xor(lsum[qt], 32);
  }

  // ---- merge group partials via LDS scratch (KV buffers dead) ----
  __syncthreads();
  const int gi = wv4 * 64 + lane;                  // 0..255 within group
  float* scr = (float*)sm + (size_t)gi * 36;       // 36 KB
  if (g == 1) {
#pragma unroll
    for (int qt = 0; qt < 2; qt++)
#pragma unroll
      for (int dt = 0; dt < 4; dt++)
#pragma unroll
        for (int j = 0; j < 4; j++) scr[qt * 16 + dt * 4 + j] = acc[qt][dt][j];
    scr[32] = mold[0]; scr[33] = mold[1];
    scr[34] = lsum[0]; scr[35] = lsum[1];
  }
  __syncthreads();
  if (g == 0) {
#pragma unroll
    for (int qt = 0; qt < 2; qt++) {
      const float mB = scr[32 + qt], lB = scr[34 + qt];
      const float mN = fmaxf(mold[qt], mB);
      const float sA = exp2f(mold[qt] - mN);
      const float sB = exp2f(mB - mN);
      const float inv = 1.f / (lsum[qt] * sA + lB * sB);
      u16* ob = att + (size_t)(b * SS + q0 + wv4 * 32 + qt * 16 + la) * DM + h * DK + lg * 4;
#pragma unroll
      for (int dt = 0; dt < 4; dt++) {
        float o0 = (acc[qt][dt][0] * sA + scr[qt * 16 + dt * 4 + 0] * sB) * inv;
        float o1 = (acc[qt][dt][1] * sA + scr[qt * 16 + dt * 4 + 1] * sB) * inv;
        float o2 = (acc[qt][dt][2] * sA + scr[qt * 16 + dt * 4 + 2] * sB) * inv;
        float o3 = (acc[qt][dt][3] * sA + scr[qt * 16 + dt * 4 + 3] * sB) * inv;
        uint2 o;
        o.x = pk2bf(o0, o1);
        o.y = pk2bf(o2, o3);
        *(uint2*)(ob + dt * 16) = o;
      }
    }
  }
}

// ---------------------------------------------------------------------------
extern "C" void kernel_launch(void* const* d_in, const int* in_sizes, int n_in,
                              void* d_out, int out_size, void* d_ws, size_t ws_size,
                              hipStream_t stream) {
  const float* x    = (const float*)d_in[0];
  const float* wq   = (const float*)d_in[1];
  const float* bq   = (const float*)d_in[2];
  const float* wk   = (const float*)d_in[3];
  const float* bk   = (const float*)d_in[4];
  const float* wv   = (const float*)d_in[5];
  const float* bv   = (const float*)d_in[6];
  const float* wo   = (const float*)d_in[7];
  const float* bo   = (const float*)d_in[8];
  const float* w1   = (const float*)d_in[9];
  const float* b1   = (const float*)d_in[10];
  const float* w2   = (const float*)d_in[11];
  const float* b2   = (const float*)d_in[12];
  const float* ln1g = (const float*)d_in[13];
  const float* ln1b = (const float*)d_in[14];
  const float* ln2g = (const float*)d_in[15];
  const float* ln2b = (const float*)d_in[16];
  float* out = (float*)d_out;

  char* w = (char*)d_ws;
  const size_t MB = 1024ull * 1024ull;
  u16*   wqkv = (u16*)(w + 0 * MB);   // [3072][1024] bf16 (Q,K,V stacked)
  u16*   wot  = (u16*)(w + 6 * MB);   // [1024][1024]
  u16*   w1t  = (u16*)(w + 8 * MB);   // [4096][1024]
  u16*   w2t  = (u16*)(w + 16 * MB);  // [1024][4096]
  float* x2   = (float*)(w + 24 * MB);// [8192][1024] f32
  u16*   hb   = (u16*)(w + 56 * MB);  // [8192][1024] (h, then h2)
  u16*   qb   = (u16*)(w + 72 * MB);  // [8192][1024]; K at +8M u16, V^T at +16M u16
  u16*   kb   = (u16*)(w + 88 * MB);
  u16*   vtb  = (u16*)(w + 104 * MB); // [4][16][64][2048] V^T per head
  u16*   atb  = (u16*)(w + 120 * MB); // [8192][1024]
  u16*   ffb  = (u16*)(w + 72 * MB);  // [8192][4096] overlays q/k/vt/att

  // 1) weight transposes (f32 -> bf16 W^T); QKV stacked into one [3072][1024]
  k_transpose<<<dim3(32, 32),  256, 0, stream>>>(wq, wqkv,               1024, 1024);
  k_transpose<<<dim3(32, 32),  256, 0, stream>>>(wk, wqkv + 1024 * 1024, 1024, 1024);
  k_transpose<<<dim3(32, 32),  256, 0, stream>>>(wv, wqkv + 2048 * 1024, 1024, 1024);
  k_transpose<<<dim3(32, 32),  256, 0, stream>>>(wo, wot, 1024, 1024);
  k_transpose<<<dim3(128, 32), 256, 0, stream>>>(w1, w1t, 1024, 4096);
  k_transpose<<<dim3(32, 128), 256, 0, stream>>>(w2, w2t, 4096, 1024);

  // 2) LN1: x -> h (bf16)
  k_layernorm<<<MROWS / 4, 256, 0, stream>>>(x, ln1g, ln1b, hb);

  // 3) fused QKV projection (Q,K row-major bf16; V per-head-transposed)
  k_gemm_bt<4><<<dim3(24, 64), 256, 0, stream>>>(hb, wqkv, bq, bk, bv, nullptr, qb,
                                                 MROWS, 3 * DM, DM);

  // 4) causal flash attention (swapped QK^T, split-KV, 8 waves)
  k_attn<<<dim3(1024), 512, 0, stream>>>(qb, kb, vtb, atb);

  // 5) O projection + residual (f32 x2)
  k_gemm_bt<1><<<dim3(8, 64), 256, 0, stream>>>(atb, wot, bo, nullptr, nullptr, x, x2,
                                                MROWS, DM, DM);

  // 6) LN2: x2 -> h2 (bf16, reuse hb)
  k_layernorm<<<MROWS / 4, 256, 0, stream>>>(x2, ln2g, ln2b, hb);

  // 7) FF1 + GELU
  k_gemm_bt<2><<<dim3(32, 64), 256, 0, stream>>>(hb, w1t, b1, nullptr, nullptr, nullptr, ffb,
                                                 MROWS, DFF, DM);

  // 8) FF2 + residual -> d_out (f32)
  k_gemm_bt<1><<<dim3(8, 64), 256, 0, stream>>>(ffb, w2t, b2, nullptr, nullptr, x2, out,
                                                MROWS, DM, DFF);
}